// Round 1
// baseline (1439.273 us; speedup 1.0000x reference)
//
#include <hip/hip_runtime.h>

#define DEV __device__ __forceinline__

typedef __attribute__((ext_vector_type(4))) float f32x4;
typedef __attribute__((ext_vector_type(8))) short short8;

DEV float bf2f(unsigned short u) {
    union { unsigned int i; float f; } c;
    c.i = ((unsigned int)u) << 16;
    return c.f;
}
DEV unsigned short f2bf(float f) {
    union { float f; unsigned int i; } c;
    c.f = f;
    unsigned int u = c.i;
    u += 0x7FFFu + ((u >> 16) & 1u);   // RTNE (finite values only here)
    return (unsigned short)(u >> 16);
}

// ---------------------------------------------------------------------------
// GEMM: C[M,256] = A[M,K] @ B[K,256], B pre-transposed+bf16 as Bt[256][ldb]
// (Bt[n][k] = B[k][n], zero-padded to ldb = ksteps*64).
// BM=64, BN=256, BK=64, 256 threads (4 waves, each owns a 64x64 C tile).
// LDS layout [row][chunk] with chunk XOR-swizzle (c ^= row&7), chunk = 8 bf16.
// ---------------------------------------------------------------------------
template<bool A_F32, bool OUT_BF16>
__launch_bounds__(256)
__global__ void gemm_k(const void* __restrict__ Aptr,
                       const unsigned short* __restrict__ Bt,
                       void* __restrict__ Cptr,
                       int M, int Kreal, int lda, int ldb, int ksteps)
{
    __shared__ unsigned short As[64 * 64];
    __shared__ unsigned short Bs[256 * 64];
    const int t    = threadIdx.x;
    const int wid  = t >> 6;
    const int lane = t & 63;
    const int m0   = blockIdx.x * 64;

    f32x4 acc[4][4] = {};

    for (int ks = 0; ks < ksteps; ++ks) {
        const int k0 = ks * 64;
        // ---- stage A ----
        if constexpr (A_F32) {
            const float* A = (const float*)Aptr;
            const int k  = lane;          // column within tile; coalesced loads
            const int kg = k0 + k;
            #pragma unroll
            for (int i = 0; i < 16; ++i) {
                const int r = i * 4 + wid;          // 0..63
                const int m = m0 + r;
                float v = 0.f;
                if (m < M && kg < Kreal) v = A[(size_t)m * lda + kg];
                As[r * 64 + ((((k >> 3) ^ (r & 7)) << 3) | (k & 7))] = f2bf(v);
            }
        } else {
            const unsigned short* A = (const unsigned short*)Aptr;
            #pragma unroll
            for (int is = 0; is < 2; ++is) {
                const int rbase = wid * 16 + is * 8;
                const int rr  = rbase + (lane >> 3);
                const int csw = (lane & 7) ^ (rr & 7);   // pre-swizzled source
                const unsigned short* src = A + (size_t)(m0 + rr) * lda + k0 + csw * 8;
                __builtin_amdgcn_global_load_lds(
                    (const __attribute__((address_space(1))) void*)src,
                    (__attribute__((address_space(3))) void*)(&As[rbase * 64]),
                    16, 0, 0);
            }
        }
        // ---- stage B (always bf16, padded => no bounds needed) ----
        #pragma unroll
        for (int is = 0; is < 8; ++is) {
            const int rbase = wid * 64 + is * 8;
            const int rr  = rbase + (lane >> 3);
            const int csw = (lane & 7) ^ (rr & 7);
            const unsigned short* src = Bt + (size_t)rr * ldb + k0 + csw * 8;
            __builtin_amdgcn_global_load_lds(
                (const __attribute__((address_space(1))) void*)src,
                (__attribute__((address_space(3))) void*)(&Bs[rbase * 64]),
                16, 0, 0);
        }
        __syncthreads();
        // ---- compute: 2 x (8 ds_read_b128 + 16 MFMA) ----
        #pragma unroll
        for (int kk = 0; kk < 2; ++kk) {
            short8 af[4], bfr[4];
            #pragma unroll
            for (int mi = 0; mi < 4; ++mi) {
                const int r   = mi * 16 + (lane & 15);
                const int csw = (kk * 4 + (lane >> 4)) ^ (r & 7);
                af[mi] = *(const short8*)(&As[r * 64 + csw * 8]);
            }
            #pragma unroll
            for (int ni = 0; ni < 4; ++ni) {
                const int r   = wid * 64 + ni * 16 + (lane & 15);
                const int csw = (kk * 4 + (lane >> 4)) ^ (r & 7);
                bfr[ni] = *(const short8*)(&Bs[r * 64 + csw * 8]);
            }
            #pragma unroll
            for (int mi = 0; mi < 4; ++mi)
                #pragma unroll
                for (int ni = 0; ni < 4; ++ni)
                    acc[mi][ni] = __builtin_amdgcn_mfma_f32_16x16x32_bf16(
                        af[mi], bfr[ni], acc[mi][ni], 0, 0, 0);
        }
        __syncthreads();
    }
    // ---- epilogue: C col = lane&15, row = (lane>>4)*4 + reg ----
    #pragma unroll
    for (int mi = 0; mi < 4; ++mi) {
        #pragma unroll
        for (int ni = 0; ni < 4; ++ni) {
            const int col = wid * 64 + ni * 16 + (lane & 15);
            #pragma unroll
            for (int rg = 0; rg < 4; ++rg) {
                const int m = m0 + mi * 16 + (lane >> 4) * 4 + rg;
                if (m < M) {
                    if constexpr (OUT_BF16)
                        ((unsigned short*)Cptr)[(size_t)m * 256 + col] = f2bf(acc[mi][ni][rg]);
                    else
                        ((float*)Cptr)[(size_t)m * 256 + col] = acc[mi][ni][rg];
                }
            }
        }
    }
}

// W[K,256] f32 -> WT[256][ldb] bf16 transposed, zero-padded k >= K.
__global__ void wtrans_k(const float* __restrict__ W, unsigned short* __restrict__ WT,
                         int K, int ldb) {
    int total = 256 * ldb;
    for (int idx = blockIdx.x * blockDim.x + threadIdx.x; idx < total;
         idx += gridDim.x * blockDim.x) {
        int n = idx / ldb, k = idx - n * ldb;
        WT[idx] = f2bf(k < K ? W[(size_t)k * 256 + n] : 0.f);
    }
}

// per-column sum & sum-of-squares into st[0..255], st[256..511]
__global__ void colstats_k(const float* __restrict__ h, float* st, int N) {
    int col = threadIdx.x;
    float s = 0.f, q = 0.f;
    for (int r = blockIdx.x; r < N; r += gridDim.x) {
        float v = h[(size_t)r * 256 + col];
        s += v; q += v * v;
    }
    atomicAdd(&st[col], s);
    atomicAdd(&st[256 + col], q);
}

__global__ void bnfinal_k(const float* __restrict__ st, const float* __restrict__ g,
                          const float* __restrict__ be, float* __restrict__ ss, float invN) {
    int c = threadIdx.x;
    float mu  = st[c] * invN;
    float var = st[256 + c] * invN - mu * mu;
    float sc  = g[c] * rsqrtf(var + 1e-5f);
    ss[c]       = sc;
    ss[256 + c] = be[c] - mu * sc;
}

// y = elu(scale*v + shift); OUT_BF16 -> bf16 buffer, else f32 (may alias input)
template<bool OUT_BF16>
__global__ void bnelu_k(const float* h, const float* ss, void* outp, int total4) {
    for (int i = blockIdx.x * blockDim.x + threadIdx.x; i < total4;
         i += gridDim.x * blockDim.x) {
        float4 v = ((const float4*)h)[i];
        int c = (i << 2) & 255;
        float4 y;
        y.x = fmaf(v.x, ss[c + 0], ss[256 + c + 0]);
        y.y = fmaf(v.y, ss[c + 1], ss[256 + c + 1]);
        y.z = fmaf(v.z, ss[c + 2], ss[256 + c + 2]);
        y.w = fmaf(v.w, ss[c + 3], ss[256 + c + 3]);
        y.x = y.x > 0.f ? y.x : expm1f(y.x);
        y.y = y.y > 0.f ? y.y : expm1f(y.y);
        y.z = y.z > 0.f ? y.z : expm1f(y.z);
        y.w = y.w > 0.f ? y.w : expm1f(y.w);
        if (OUT_BF16) {
            ushort4 o;
            o.x = f2bf(y.x); o.y = f2bf(y.y); o.z = f2bf(y.z); o.w = f2bf(y.w);
            ((ushort4*)outp)[i] = o;
        } else {
            ((float4*)outp)[i] = y;
        }
    }
}

// per-row dot products with att vectors (wave per row)
__global__ void adot_k(const unsigned short* __restrict__ xl, const float* __restrict__ as_,
                       const float* __restrict__ ad_, float* __restrict__ a_src,
                       float* __restrict__ a_dst, int N) {
    int w = (blockIdx.x * blockDim.x + threadIdx.x) >> 6;
    int lane = threadIdx.x & 63;
    if (w >= N) return;
    ushort4 v = *(const ushort4*)(xl + (size_t)w * 256 + lane * 4);
    float4 s4 = *(const float4*)(as_ + lane * 4);
    float4 d4 = *(const float4*)(ad_ + lane * 4);
    float x0 = bf2f(v.x), x1 = bf2f(v.y), x2 = bf2f(v.z), x3 = bf2f(v.w);
    float ps = x0 * s4.x + x1 * s4.y + x2 * s4.z + x3 * s4.w;
    float pd = x0 * d4.x + x1 * d4.y + x2 * d4.z + x3 * d4.w;
    #pragma unroll
    for (int off = 32; off; off >>= 1) {
        ps += __shfl_xor(ps, off);
        pd += __shfl_xor(pd, off);
    }
    if (lane == 0) { a_src[w] = ps; a_dst[w] = pd; }
}

// one wave per destination node: softmax over incoming edges + weighted gather
__global__ void gat_k(const unsigned short* __restrict__ xl, const float* __restrict__ a_src,
                      const float* __restrict__ a_dst, const int* __restrict__ csr,
                      const int* __restrict__ indptr, float* __restrict__ out, int N) {
    int d = (blockIdx.x * blockDim.x + threadIdx.x) >> 6;
    int lane = threadIdx.x & 63;
    if (d >= N) return;
    int beg = indptr[d], end = indptr[d + 1];
    float adst = a_dst[d];
    float mx = -1e30f;
    for (int i = beg + lane; i < end; i += 64) {
        float e = a_src[csr[i]] + adst;
        e = e > 0.f ? e : 0.2f * e;
        mx = fmaxf(mx, e);
    }
    #pragma unroll
    for (int off = 32; off; off >>= 1) mx = fmaxf(mx, __shfl_xor(mx, off));
    float sm = 0.f;
    for (int i = beg + lane; i < end; i += 64) {
        float e = a_src[csr[i]] + adst;
        e = e > 0.f ? e : 0.2f * e;
        sm += __expf(e - mx);
    }
    #pragma unroll
    for (int off = 32; off; off >>= 1) sm += __shfl_xor(sm, off);
    float inv = 1.f / (sm + 1e-16f);
    float4 acc = {0.f, 0.f, 0.f, 0.f};
    for (int i = beg; i < end; ++i) {
        int s = csr[i];                       // uniform across wave
        float e = a_src[s] + adst;
        e = e > 0.f ? e : 0.2f * e;
        float al = __expf(e - mx) * inv;
        ushort4 v = *(const ushort4*)(xl + (size_t)s * 256 + lane * 4);
        acc.x += al * bf2f(v.x);
        acc.y += al * bf2f(v.y);
        acc.z += al * bf2f(v.z);
        acc.w += al * bf2f(v.w);
    }
    *(float4*)(out + (size_t)d * 256 + lane * 4) = acc;
}

// ---- CSR build ----
__global__ void hist_k(const int* __restrict__ edges, int* deg, int E, int N) {
    int total = E + N;
    for (int i = blockIdx.x * blockDim.x + threadIdx.x; i < total;
         i += gridDim.x * blockDim.x) {
        int dd = (i < E) ? edges[E + i] : (i - E);
        atomicAdd(&deg[dd], 1);
    }
}

__global__ void scan1_k(const int* __restrict__ deg, int* iscan, int* bsum, int N) {
    int i = blockIdx.x * 256 + threadIdx.x;
    int lane = threadIdx.x & 63, wid = threadIdx.x >> 6;
    int v = (i < N) ? deg[i] : 0;
    #pragma unroll
    for (int off = 1; off < 64; off <<= 1) {
        int u = __shfl_up(v, off);
        if (lane >= off) v += u;
    }
    __shared__ int wsum[4];
    if (lane == 63) wsum[wid] = v;
    __syncthreads();
    #pragma unroll
    for (int w = 0; w < 3; ++w) if (wid > w) v += wsum[w];
    if (i < N) iscan[i] = v;
    if (threadIdx.x == 255) bsum[blockIdx.x] = v;
}

__global__ void scan2_k(int* bsum, int nb) {   // nb <= 256
    int t = threadIdx.x;
    int lane = t & 63, wid = t >> 6;
    int v = (t < nb) ? bsum[t] : 0;
    int orig = v;
    #pragma unroll
    for (int off = 1; off < 64; off <<= 1) {
        int u = __shfl_up(v, off);
        if (lane >= off) v += u;
    }
    __shared__ int wsum[4];
    if (lane == 63) wsum[wid] = v;
    __syncthreads();
    #pragma unroll
    for (int w = 0; w < 3; ++w) if (wid > w) v += wsum[w];
    if (t < nb) bsum[t] = v - orig;            // exclusive block offsets
}

__global__ void scan3_k(const int* __restrict__ iscan, const int* __restrict__ boff,
                        int* indptr, int N) {
    int i = blockIdx.x * 256 + threadIdx.x;
    if (i < N) indptr[i + 1] = iscan[i] + boff[blockIdx.x];
    if (i == 0) indptr[0] = 0;
}

__global__ void copy_k(const int* __restrict__ a, int* b, int N) {
    for (int i = blockIdx.x * blockDim.x + threadIdx.x; i < N;
         i += gridDim.x * blockDim.x) b[i] = a[i];
}

__global__ void scatter_k(const int* __restrict__ edges, int* pos, int* csr, int E, int N) {
    int total = E + N;
    for (int i = blockIdx.x * blockDim.x + threadIdx.x; i < total;
         i += gridDim.x * blockDim.x) {
        int s  = (i < E) ? edges[i]     : (i - E);
        int dd = (i < E) ? edges[E + i] : (i - E);
        int slot = atomicAdd(&pos[dd], 1);
        csr[slot] = s;
    }
}

// ---------------------------------------------------------------------------
extern "C" void kernel_launch(void* const* d_in, const int* in_sizes, int n_in,
                              void* d_out, int out_size, void* d_ws, size_t ws_size,
                              hipStream_t stream) {
    const float* x     = (const float*)d_in[0];
    const int*   edges = (const int*)d_in[1];
    const float* W1 = (const float*)d_in[2];
    const float* W2 = (const float*)d_in[4];
    const float* W3 = (const float*)d_in[6];
    const float* g1 = (const float*)d_in[8],  *be1 = (const float*)d_in[9];
    const float* g2 = (const float*)d_in[10], *be2 = (const float*)d_in[11];
    const float* g3 = (const float*)d_in[12], *be3 = (const float*)d_in[13];
    const float* Wg1 = (const float*)d_in[14];
    const float* as1 = (const float*)d_in[15], *ad1 = (const float*)d_in[16];
    const float* g4 = (const float*)d_in[18], *be4 = (const float*)d_in[19];
    const float* Wg2 = (const float*)d_in[20];
    const float* as2 = (const float*)d_in[21], *ad2 = (const float*)d_in[22];
    const float* g5 = (const float*)d_in[24], *be5 = (const float*)d_in[25];

    const int N    = out_size / 256;
    const int K1   = in_sizes[0] / N;
    const int E    = in_sizes[1] / 2;
    const int Etot = E + N;
    const int ks1  = (K1 + 63) / 64;
    const int ldb1 = ks1 * 64;

    // workspace carve (256B aligned)
    char* p = (char*)d_ws;
    auto alloc = [&](size_t bytes) {
        char* r = p;
        p += (bytes + 255) & ~(size_t)255;
        return r;
    };
    unsigned short* W1T  = (unsigned short*)alloc((size_t)256 * ldb1 * 2);
    unsigned short* W2T  = (unsigned short*)alloc(256 * 256 * 2);
    unsigned short* W3T  = (unsigned short*)alloc(256 * 256 * 2);
    unsigned short* Wg1T = (unsigned short*)alloc(256 * 256 * 2);
    unsigned short* Wg2T = (unsigned short*)alloc(256 * 256 * 2);
    unsigned short* hn   = (unsigned short*)alloc((size_t)N * 256 * 2);
    unsigned short* xl   = (unsigned short*)alloc((size_t)N * 256 * 2);
    float* a_src  = (float*)alloc((size_t)N * 4);
    float* a_dst  = (float*)alloc((size_t)N * 4);
    int*   deg    = (int*)alloc((size_t)N * 4);
    int*   iscan  = (int*)alloc((size_t)N * 4);
    int*   bsum   = (int*)alloc(1024);
    int*   indptr = (int*)alloc((size_t)(N + 1) * 4);
    int*   pos    = (int*)alloc((size_t)N * 4);
    int*   csr    = (int*)alloc((size_t)Etot * 4);
    float* st     = (float*)alloc(512 * 4);
    float* ss     = (float*)alloc(512 * 4);
    (void)alloc(65536); // tail guard for benign over-reads
    float* out = (float*)d_out;

    const int nb = (N + 255) / 256;
    const int eg = (Etot + 255) / 256;
    const int gb = (N + 63) / 64;
    const int t4 = N * 64;                    // (N*256)/4
    const int bg4 = (t4 + 255) / 256;

    // ---- graph CSR (shared by both GAT layers) ----
    hipMemsetAsync(deg, 0, (size_t)N * 4, stream);
    hist_k<<<eg, 256, 0, stream>>>(edges, deg, E, N);
    scan1_k<<<nb, 256, 0, stream>>>(deg, iscan, bsum, N);
    scan2_k<<<1, 256, 0, stream>>>(bsum, nb);
    scan3_k<<<nb, 256, 0, stream>>>(iscan, bsum, indptr, N);
    copy_k<<<nb, 256, 0, stream>>>(indptr, pos, N);
    scatter_k<<<eg, 256, 0, stream>>>(edges, pos, csr, E, N);

    // ---- weight prep (transpose + bf16) ----
    wtrans_k<<<(256 * ldb1 + 255) / 256, 256, 0, stream>>>(W1, W1T, K1, ldb1);
    wtrans_k<<<256, 256, 0, stream>>>(W2, W2T, 256, 256);
    wtrans_k<<<256, 256, 0, stream>>>(W3, W3T, 256, 256);
    wtrans_k<<<256, 256, 0, stream>>>(Wg1, Wg1T, 256, 256);
    wtrans_k<<<256, 256, 0, stream>>>(Wg2, Wg2T, 256, 256);

    const float invN = 1.f / (float)N;

    // ---- layer 1: x @ W1 -> BN -> ELU (bias cancels in BN) ----
    gemm_k<true, false><<<gb, 256, 0, stream>>>(x, W1T, out, N, K1, K1, ldb1, ks1);
    hipMemsetAsync(st, 0, 2048, stream);
    colstats_k<<<256, 256, 0, stream>>>(out, st, N);
    bnfinal_k<<<1, 256, 0, stream>>>(st, g1, be1, ss, invN);
    bnelu_k<true><<<bg4, 256, 0, stream>>>(out, ss, hn, t4);

    // ---- layer 2 ----
    gemm_k<false, false><<<gb, 256, 0, stream>>>(hn, W2T, out, N, 256, 256, 256, 4);
    hipMemsetAsync(st, 0, 2048, stream);
    colstats_k<<<256, 256, 0, stream>>>(out, st, N);
    bnfinal_k<<<1, 256, 0, stream>>>(st, g2, be2, ss, invN);
    bnelu_k<true><<<bg4, 256, 0, stream>>>(out, ss, hn, t4);

    // ---- layer 3 ----
    gemm_k<false, false><<<gb, 256, 0, stream>>>(hn, W3T, out, N, 256, 256, 256, 4);
    hipMemsetAsync(st, 0, 2048, stream);
    colstats_k<<<256, 256, 0, stream>>>(out, st, N);
    bnfinal_k<<<1, 256, 0, stream>>>(st, g3, be3, ss, invN);
    bnelu_k<true><<<bg4, 256, 0, stream>>>(out, ss, hn, t4);

    // ---- GAT layer 1 ----
    gemm_k<false, true><<<gb, 256, 0, stream>>>(hn, Wg1T, xl, N, 256, 256, 256, 4);
    adot_k<<<(N + 3) / 4, 256, 0, stream>>>(xl, as1, ad1, a_src, a_dst, N);
    gat_k<<<(N + 3) / 4, 256, 0, stream>>>(xl, a_src, a_dst, csr, indptr, out, N);
    hipMemsetAsync(st, 0, 2048, stream);
    colstats_k<<<256, 256, 0, stream>>>(out, st, N);
    bnfinal_k<<<1, 256, 0, stream>>>(st, g4, be4, ss, invN);
    bnelu_k<true><<<bg4, 256, 0, stream>>>(out, ss, hn, t4);

    // ---- GAT layer 2 ----
    gemm_k<false, true><<<gb, 256, 0, stream>>>(hn, Wg2T, xl, N, 256, 256, 256, 4);
    adot_k<<<(N + 3) / 4, 256, 0, stream>>>(xl, as2, ad2, a_src, a_dst, N);
    gat_k<<<(N + 3) / 4, 256, 0, stream>>>(xl, a_src, a_dst, csr, indptr, out, N);
    hipMemsetAsync(st, 0, 2048, stream);
    colstats_k<<<256, 256, 0, stream>>>(out, st, N);
    bnfinal_k<<<1, 256, 0, stream>>>(st, g5, be5, ss, invN);
    bnelu_k<false><<<bg4, 256, 0, stream>>>(out, ss, out, t4);  // final, in-place f32
}

// Round 2
// 1333.640 us; speedup vs baseline: 1.0792x; 1.0792x over previous
//
#include <hip/hip_runtime.h>

#define DEV __device__ __forceinline__

typedef __attribute__((ext_vector_type(4))) float f32x4;
typedef __attribute__((ext_vector_type(8))) short short8;

DEV float bf2f(unsigned short u) {
    union { unsigned int i; float f; } c;
    c.i = ((unsigned int)u) << 16;
    return c.f;
}
DEV unsigned short f2bf(float f) {
    union { float f; unsigned int i; } c;
    c.f = f;
    unsigned int u = c.i;
    u += 0x7FFFu + ((u >> 16) & 1u);   // RTNE (finite values only here)
    return (unsigned short)(u >> 16);
}

// ---------------------------------------------------------------------------
// GEMM: C[M,256] = A[M,K] @ B[K,256], B pre-transposed+bf16 as Bt[256][ldb].
// BM=64, BN=256, BK=64, 256 threads (4 waves, each owns a 64x64 C tile).
// Double-buffered LDS, prefetch-before-compute (T3 minimum 2-phase).
// f32 A path: register-staged (T14: load early, cvt+ds_write after MFMAs).
// LDS layout [row][chunk] with chunk XOR-swizzle (c ^= row&7), chunk = 8 bf16.
// ---------------------------------------------------------------------------
template<bool A_F32, bool OUT_BF16>
__launch_bounds__(256)
__global__ void gemm_k(const void* __restrict__ Aptr,
                       const unsigned short* __restrict__ Bt,
                       void* __restrict__ Cptr,
                       int M, int Kreal, int lda, int ldb, int ksteps)
{
    __shared__ __align__(16) unsigned short As[2][64 * 64];
    __shared__ __align__(16) unsigned short Bs[2][256 * 64];
    const int t    = threadIdx.x;
    const int wid  = t >> 6;
    const int lane = t & 63;
    const int m0   = blockIdx.x * 64;

    const float* Af          = (const float*)Aptr;
    const unsigned short* Ab = (const unsigned short*)Aptr;

    f32x4 acc[4][4] = {};
    float ar[16];   // f32-A register staging (statically indexed only)

    // ---- staging helpers ----
    auto stageB = [&](int buf, int ks) {
        const int k0 = ks * 64;
        #pragma unroll
        for (int is = 0; is < 8; ++is) {
            const int rbase = wid * 64 + is * 8;
            const int rr  = rbase + (lane >> 3);
            const int csw = (lane & 7) ^ (rr & 7);         // pre-swizzled source
            __builtin_amdgcn_global_load_lds(
                (const __attribute__((address_space(1))) void*)(Bt + (size_t)rr * ldb + k0 + csw * 8),
                (__attribute__((address_space(3))) void*)(&Bs[buf][rbase * 64]),
                16, 0, 0);
        }
    };
    auto stageAb = [&](int buf, int ks) {
        const int k0 = ks * 64;
        #pragma unroll
        for (int is = 0; is < 2; ++is) {
            const int rbase = wid * 16 + is * 8;
            const int rr  = rbase + (lane >> 3);
            const int csw = (lane & 7) ^ (rr & 7);
            __builtin_amdgcn_global_load_lds(
                (const __attribute__((address_space(1))) void*)(Ab + (size_t)(m0 + rr) * lda + k0 + csw * 8),
                (__attribute__((address_space(3))) void*)(&As[buf][rbase * 64]),
                16, 0, 0);
        }
    };
    auto loadAf = [&](int ks) {        // issue 4 coalesced dwordx4 -> ar[]
        const int k0 = ks * 64;
        #pragma unroll
        for (int i = 0; i < 4; ++i) {
            const int tt  = t + i * 256;
            const int row = tt >> 4;            // 0..63
            const int cg  = tt & 15;            // 4-float column group
            const int m   = m0 + row;
            const int kg  = k0 + cg * 4;
            if (m < M && kg + 3 < Kreal) {
                *(f32x4*)&ar[i * 4] = *(const f32x4*)(Af + (size_t)m * lda + kg);
            } else {
                #pragma unroll
                for (int j = 0; j < 4; ++j)
                    ar[i * 4 + j] = (m < M && kg + j < Kreal)
                                    ? Af[(size_t)m * lda + kg + j] : 0.f;
            }
        }
    };
    auto writeAf = [&](int buf) {      // cvt + swizzled ds_write_b64
        #pragma unroll
        for (int i = 0; i < 4; ++i) {
            const int tt  = t + i * 256;
            const int row = tt >> 4;
            const int cg  = tt & 15;
            uint2 pk;
            pk.x = (unsigned int)f2bf(ar[i * 4 + 0]) | ((unsigned int)f2bf(ar[i * 4 + 1]) << 16);
            pk.y = (unsigned int)f2bf(ar[i * 4 + 2]) | ((unsigned int)f2bf(ar[i * 4 + 3]) << 16);
            *(uint2*)&As[buf][row * 64 + ((((cg >> 1) ^ (row & 7)) << 3) | ((cg & 1) << 2))] = pk;
        }
    };
    auto compute = [&](int buf) {
        #pragma unroll
        for (int kk = 0; kk < 2; ++kk) {
            short8 af[4], bfr[4];
            #pragma unroll
            for (int mi = 0; mi < 4; ++mi) {
                const int r   = mi * 16 + (lane & 15);
                const int csw = (kk * 4 + (lane >> 4)) ^ (r & 7);
                af[mi] = *(const short8*)(&As[buf][r * 64 + csw * 8]);
            }
            #pragma unroll
            for (int ni = 0; ni < 4; ++ni) {
                const int r   = wid * 64 + ni * 16 + (lane & 15);
                const int csw = (kk * 4 + (lane >> 4)) ^ (r & 7);
                bfr[ni] = *(const short8*)(&Bs[buf][r * 64 + csw * 8]);
            }
            #pragma unroll
            for (int mi = 0; mi < 4; ++mi)
                #pragma unroll
                for (int ni = 0; ni < 4; ++ni)
                    acc[mi][ni] = __builtin_amdgcn_mfma_f32_16x16x32_bf16(
                        af[mi], bfr[ni], acc[mi][ni], 0, 0, 0);
        }
    };

    // ---- prologue: fill buffer 0 ----
    if constexpr (A_F32) { loadAf(0); writeAf(0); }
    else                 stageAb(0, 0);
    stageB(0, 0);
    __syncthreads();

    // ---- main loop: prefetch(cur^1) || compute(cur) ----
    int cur = 0;
    for (int ks = 0; ks < ksteps; ++ks) {
        const bool hasNext = (ks + 1 < ksteps);
        if (hasNext) {
            if constexpr (A_F32) loadAf(ks + 1);
            else                 stageAb(cur ^ 1, ks + 1);
            stageB(cur ^ 1, ks + 1);
        }
        compute(cur);
        if (A_F32 && hasNext) writeAf(cur ^ 1);   // waits only the 4 A loads
        __syncthreads();
        cur ^= 1;
    }

    // ---- epilogue: C col = lane&15, row = (lane>>4)*4 + reg ----
    #pragma unroll
    for (int mi = 0; mi < 4; ++mi) {
        #pragma unroll
        for (int ni = 0; ni < 4; ++ni) {
            const int col = wid * 64 + ni * 16 + (lane & 15);
            #pragma unroll
            for (int rg = 0; rg < 4; ++rg) {
                const int m = m0 + mi * 16 + (lane >> 4) * 4 + rg;
                if (m < M) {
                    if constexpr (OUT_BF16)
                        ((unsigned short*)Cptr)[(size_t)m * 256 + col] = f2bf(acc[mi][ni][rg]);
                    else
                        ((float*)Cptr)[(size_t)m * 256 + col] = acc[mi][ni][rg];
                }
            }
        }
    }
}

// W[K,256] f32 -> WT[256][ldb] bf16 transposed, zero-padded k >= K.
__global__ void wtrans_k(const float* __restrict__ W, unsigned short* __restrict__ WT,
                         int K, int ldb) {
    int total = 256 * ldb;
    for (int idx = blockIdx.x * blockDim.x + threadIdx.x; idx < total;
         idx += gridDim.x * blockDim.x) {
        int n = idx / ldb, k = idx - n * ldb;
        WT[idx] = f2bf(k < K ? W[(size_t)k * 256 + n] : 0.f);
    }
}

// per-column sum & sum-of-squares into st[0..255], st[256..511].
// Grid-stride float4 with per-thread fixed column group (stride % 64 == 0),
// block-level LDS reduction, then 512 atomics per block.
__global__ void colstats_k(const float* __restrict__ h, float* st, int total4) {
    const int gid    = blockIdx.x * 256 + threadIdx.x;
    const int stride = gridDim.x * 256;          // multiple of 64 by launch config
    float4 s = {0.f, 0.f, 0.f, 0.f}, q = {0.f, 0.f, 0.f, 0.f};
    for (int i = gid; i < total4; i += stride) {
        float4 v = ((const float4*)h)[i];
        s.x += v.x; s.y += v.y; s.z += v.z; s.w += v.w;
        q.x += v.x * v.x; q.y += v.y * v.y; q.z += v.z * v.z; q.w += v.w * v.w;
    }
    __shared__ float red[2][4][64][4];
    const int wid = threadIdx.x >> 6, lane = threadIdx.x & 63;
    *(float4*)&red[0][wid][lane][0] = s;
    *(float4*)&red[1][wid][lane][0] = q;
    __syncthreads();
    if (wid == 0) {
        float4 s0 = *(float4*)&red[0][0][lane][0];
        float4 q0 = *(float4*)&red[1][0][lane][0];
        #pragma unroll
        for (int w = 1; w < 4; ++w) {
            float4 sw = *(float4*)&red[0][w][lane][0];
            float4 qw = *(float4*)&red[1][w][lane][0];
            s0.x += sw.x; s0.y += sw.y; s0.z += sw.z; s0.w += sw.w;
            q0.x += qw.x; q0.y += qw.y; q0.z += qw.z; q0.w += qw.w;
        }
        atomicAdd(&st[lane * 4 + 0], s0.x);
        atomicAdd(&st[lane * 4 + 1], s0.y);
        atomicAdd(&st[lane * 4 + 2], s0.z);
        atomicAdd(&st[lane * 4 + 3], s0.w);
        atomicAdd(&st[256 + lane * 4 + 0], q0.x);
        atomicAdd(&st[256 + lane * 4 + 1], q0.y);
        atomicAdd(&st[256 + lane * 4 + 2], q0.z);
        atomicAdd(&st[256 + lane * 4 + 3], q0.w);
    }
}

__global__ void bnfinal_k(const float* __restrict__ st, const float* __restrict__ g,
                          const float* __restrict__ be, float* __restrict__ ss, float invN) {
    int c = threadIdx.x;
    float mu  = st[c] * invN;
    float var = st[256 + c] * invN - mu * mu;
    float sc  = g[c] * rsqrtf(var + 1e-5f);
    ss[c]       = sc;
    ss[256 + c] = be[c] - mu * sc;
}

// y = elu(scale*v + shift); OUT_BF16 -> bf16 buffer, else f32 (may alias input)
template<bool OUT_BF16>
__global__ void bnelu_k(const float* h, const float* ss, void* outp, int total4) {
    for (int i = blockIdx.x * blockDim.x + threadIdx.x; i < total4;
         i += gridDim.x * blockDim.x) {
        float4 v = ((const float4*)h)[i];
        int c = (i << 2) & 255;
        float4 y;
        y.x = fmaf(v.x, ss[c + 0], ss[256 + c + 0]);
        y.y = fmaf(v.y, ss[c + 1], ss[256 + c + 1]);
        y.z = fmaf(v.z, ss[c + 2], ss[256 + c + 2]);
        y.w = fmaf(v.w, ss[c + 3], ss[256 + c + 3]);
        y.x = y.x > 0.f ? y.x : expm1f(y.x);
        y.y = y.y > 0.f ? y.y : expm1f(y.y);
        y.z = y.z > 0.f ? y.z : expm1f(y.z);
        y.w = y.w > 0.f ? y.w : expm1f(y.w);
        if (OUT_BF16) {
            ushort4 o;
            o.x = f2bf(y.x); o.y = f2bf(y.y); o.z = f2bf(y.z); o.w = f2bf(y.w);
            ((ushort4*)outp)[i] = o;
        } else {
            ((float4*)outp)[i] = y;
        }
    }
}

// per-row dot products with att vectors (wave per row)
__global__ void adot_k(const unsigned short* __restrict__ xl, const float* __restrict__ as_,
                       const float* __restrict__ ad_, float* __restrict__ a_src,
                       float* __restrict__ a_dst, int N) {
    int w = (blockIdx.x * blockDim.x + threadIdx.x) >> 6;
    int lane = threadIdx.x & 63;
    if (w >= N) return;
    ushort4 v = *(const ushort4*)(xl + (size_t)w * 256 + lane * 4);
    float4 s4 = *(const float4*)(as_ + lane * 4);
    float4 d4 = *(const float4*)(ad_ + lane * 4);
    float x0 = bf2f(v.x), x1 = bf2f(v.y), x2 = bf2f(v.z), x3 = bf2f(v.w);
    float ps = x0 * s4.x + x1 * s4.y + x2 * s4.z + x3 * s4.w;
    float pd = x0 * d4.x + x1 * d4.y + x2 * d4.z + x3 * d4.w;
    #pragma unroll
    for (int off = 32; off; off >>= 1) {
        ps += __shfl_xor(ps, off);
        pd += __shfl_xor(pd, off);
    }
    if (lane == 0) { a_src[w] = ps; a_dst[w] = pd; }
}

// one wave per destination node: softmax over incoming edges + weighted gather
__global__ void gat_k(const unsigned short* __restrict__ xl, const float* __restrict__ a_src,
                      const float* __restrict__ a_dst, const int* __restrict__ csr,
                      const int* __restrict__ indptr, float* __restrict__ out, int N) {
    int d = (blockIdx.x * blockDim.x + threadIdx.x) >> 6;
    int lane = threadIdx.x & 63;
    if (d >= N) return;
    int beg = indptr[d], end = indptr[d + 1];
    float adst = a_dst[d];
    float mx = -1e30f;
    for (int i = beg + lane; i < end; i += 64) {
        float e = a_src[csr[i]] + adst;
        e = e > 0.f ? e : 0.2f * e;
        mx = fmaxf(mx, e);
    }
    #pragma unroll
    for (int off = 32; off; off >>= 1) mx = fmaxf(mx, __shfl_xor(mx, off));
    float sm = 0.f;
    for (int i = beg + lane; i < end; i += 64) {
        float e = a_src[csr[i]] + adst;
        e = e > 0.f ? e : 0.2f * e;
        sm += __expf(e - mx);
    }
    #pragma unroll
    for (int off = 32; off; off >>= 1) sm += __shfl_xor(sm, off);
    float inv = 1.f / (sm + 1e-16f);
    float4 acc = {0.f, 0.f, 0.f, 0.f};
    for (int i = beg; i < end; ++i) {
        int s = csr[i];                       // uniform across wave
        float e = a_src[s] + adst;
        e = e > 0.f ? e : 0.2f * e;
        float al = __expf(e - mx) * inv;
        ushort4 v = *(const ushort4*)(xl + (size_t)s * 256 + lane * 4);
        acc.x += al * bf2f(v.x);
        acc.y += al * bf2f(v.y);
        acc.z += al * bf2f(v.z);
        acc.w += al * bf2f(v.w);
    }
    *(float4*)(out + (size_t)d * 256 + lane * 4) = acc;
}

// ---- CSR build ----
__global__ void hist_k(const int* __restrict__ edges, int* deg, int E, int N) {
    int total = E + N;
    for (int i = blockIdx.x * blockDim.x + threadIdx.x; i < total;
         i += gridDim.x * blockDim.x) {
        int dd = (i < E) ? edges[E + i] : (i - E);
        atomicAdd(&deg[dd], 1);
    }
}

__global__ void scan1_k(const int* __restrict__ deg, int* iscan, int* bsum, int N) {
    int i = blockIdx.x * 256 + threadIdx.x;
    int lane = threadIdx.x & 63, wid = threadIdx.x >> 6;
    int v = (i < N) ? deg[i] : 0;
    #pragma unroll
    for (int off = 1; off < 64; off <<= 1) {
        int u = __shfl_up(v, off);
        if (lane >= off) v += u;
    }
    __shared__ int wsum[4];
    if (lane == 63) wsum[wid] = v;
    __syncthreads();
    #pragma unroll
    for (int w = 0; w < 3; ++w) if (wid > w) v += wsum[w];
    if (i < N) iscan[i] = v;
    if (threadIdx.x == 255) bsum[blockIdx.x] = v;
}

__global__ void scan2_k(int* bsum, int nb) {   // nb <= 256
    int t = threadIdx.x;
    int lane = t & 63, wid = t >> 6;
    int v = (t < nb) ? bsum[t] : 0;
    int orig = v;
    #pragma unroll
    for (int off = 1; off < 64; off <<= 1) {
        int u = __shfl_up(v, off);
        if (lane >= off) v += u;
    }
    __shared__ int wsum[4];
    if (lane == 63) wsum[wid] = v;
    __syncthreads();
    #pragma unroll
    for (int w = 0; w < 3; ++w) if (wid > w) v += wsum[w];
    if (t < nb) bsum[t] = v - orig;            // exclusive block offsets
}

__global__ void scan3_k(const int* __restrict__ iscan, const int* __restrict__ boff,
                        int* indptr, int N) {
    int i = blockIdx.x * 256 + threadIdx.x;
    if (i < N) indptr[i + 1] = iscan[i] + boff[blockIdx.x];
    if (i == 0) indptr[0] = 0;
}

__global__ void copy_k(const int* __restrict__ a, int* b, int N) {
    for (int i = blockIdx.x * blockDim.x + threadIdx.x; i < N;
         i += gridDim.x * blockDim.x) b[i] = a[i];
}

__global__ void scatter_k(const int* __restrict__ edges, int* pos, int* csr, int E, int N) {
    int total = E + N;
    for (int i = blockIdx.x * blockDim.x + threadIdx.x; i < total;
         i += gridDim.x * blockDim.x) {
        int s  = (i < E) ? edges[i]     : (i - E);
        int dd = (i < E) ? edges[E + i] : (i - E);
        int slot = atomicAdd(&pos[dd], 1);
        csr[slot] = s;
    }
}

// ---------------------------------------------------------------------------
extern "C" void kernel_launch(void* const* d_in, const int* in_sizes, int n_in,
                              void* d_out, int out_size, void* d_ws, size_t ws_size,
                              hipStream_t stream) {
    const float* x     = (const float*)d_in[0];
    const int*   edges = (const int*)d_in[1];
    const float* W1 = (const float*)d_in[2];
    const float* W2 = (const float*)d_in[4];
    const float* W3 = (const float*)d_in[6];
    const float* g1 = (const float*)d_in[8],  *be1 = (const float*)d_in[9];
    const float* g2 = (const float*)d_in[10], *be2 = (const float*)d_in[11];
    const float* g3 = (const float*)d_in[12], *be3 = (const float*)d_in[13];
    const float* Wg1 = (const float*)d_in[14];
    const float* as1 = (const float*)d_in[15], *ad1 = (const float*)d_in[16];
    const float* g4 = (const float*)d_in[18], *be4 = (const float*)d_in[19];
    const float* Wg2 = (const float*)d_in[20];
    const float* as2 = (const float*)d_in[21], *ad2 = (const float*)d_in[22];
    const float* g5 = (const float*)d_in[24], *be5 = (const float*)d_in[25];

    const int N    = out_size / 256;
    const int K1   = in_sizes[0] / N;
    const int E    = in_sizes[1] / 2;
    const int Etot = E + N;
    const int ks1  = (K1 + 63) / 64;
    const int ldb1 = ks1 * 64;

    // workspace carve (256B aligned)
    char* p = (char*)d_ws;
    auto alloc = [&](size_t bytes) {
        char* r = p;
        p += (bytes + 255) & ~(size_t)255;
        return r;
    };
    unsigned short* W1T  = (unsigned short*)alloc((size_t)256 * ldb1 * 2);
    unsigned short* W2T  = (unsigned short*)alloc(256 * 256 * 2);
    unsigned short* W3T  = (unsigned short*)alloc(256 * 256 * 2);
    unsigned short* Wg1T = (unsigned short*)alloc(256 * 256 * 2);
    unsigned short* Wg2T = (unsigned short*)alloc(256 * 256 * 2);
    unsigned short* hn   = (unsigned short*)alloc((size_t)N * 256 * 2);
    unsigned short* xl   = (unsigned short*)alloc((size_t)N * 256 * 2);
    float* a_src  = (float*)alloc((size_t)N * 4);
    float* a_dst  = (float*)alloc((size_t)N * 4);
    int*   deg    = (int*)alloc((size_t)N * 4);
    int*   iscan  = (int*)alloc((size_t)N * 4);
    int*   bsum   = (int*)alloc(1024);
    int*   indptr = (int*)alloc((size_t)(N + 1) * 4);
    int*   pos    = (int*)alloc((size_t)N * 4);
    int*   csr    = (int*)alloc((size_t)Etot * 4);
    float* st     = (float*)alloc(512 * 4);
    float* ss     = (float*)alloc(512 * 4);
    (void)alloc(65536); // tail guard for benign over-reads
    float* out = (float*)d_out;

    const int nb = (N + 255) / 256;
    const int eg = (Etot + 255) / 256;
    const int gb = (N + 63) / 64;
    const int t4 = N * 64;                    // (N*256)/4
    const int bg4 = (t4 + 255) / 256;

    // ---- graph CSR (shared by both GAT layers) ----
    hipMemsetAsync(deg, 0, (size_t)N * 4, stream);
    hist_k<<<eg, 256, 0, stream>>>(edges, deg, E, N);
    scan1_k<<<nb, 256, 0, stream>>>(deg, iscan, bsum, N);
    scan2_k<<<1, 256, 0, stream>>>(bsum, nb);
    scan3_k<<<nb, 256, 0, stream>>>(iscan, bsum, indptr, N);
    copy_k<<<nb, 256, 0, stream>>>(indptr, pos, N);
    scatter_k<<<eg, 256, 0, stream>>>(edges, pos, csr, E, N);

    // ---- weight prep (transpose + bf16) ----
    wtrans_k<<<(256 * ldb1 + 255) / 256, 256, 0, stream>>>(W1, W1T, K1, ldb1);
    wtrans_k<<<256, 256, 0, stream>>>(W2, W2T, 256, 256);
    wtrans_k<<<256, 256, 0, stream>>>(W3, W3T, 256, 256);
    wtrans_k<<<256, 256, 0, stream>>>(Wg1, Wg1T, 256, 256);
    wtrans_k<<<256, 256, 0, stream>>>(Wg2, Wg2T, 256, 256);

    const float invN = 1.f / (float)N;

    // ---- layer 1: x @ W1 -> BN -> ELU (bias cancels in BN) ----
    gemm_k<true, false><<<gb, 256, 0, stream>>>(x, W1T, out, N, K1, K1, ldb1, ks1);
    hipMemsetAsync(st, 0, 2048, stream);
    colstats_k<<<1024, 256, 0, stream>>>(out, st, t4);
    bnfinal_k<<<1, 256, 0, stream>>>(st, g1, be1, ss, invN);
    bnelu_k<true><<<bg4, 256, 0, stream>>>(out, ss, hn, t4);

    // ---- layer 2 ----
    gemm_k<false, false><<<gb, 256, 0, stream>>>(hn, W2T, out, N, 256, 256, 256, 4);
    hipMemsetAsync(st, 0, 2048, stream);
    colstats_k<<<1024, 256, 0, stream>>>(out, st, t4);
    bnfinal_k<<<1, 256, 0, stream>>>(st, g2, be2, ss, invN);
    bnelu_k<true><<<bg4, 256, 0, stream>>>(out, ss, hn, t4);

    // ---- layer 3 ----
    gemm_k<false, false><<<gb, 256, 0, stream>>>(hn, W3T, out, N, 256, 256, 256, 4);
    hipMemsetAsync(st, 0, 2048, stream);
    colstats_k<<<1024, 256, 0, stream>>>(out, st, t4);
    bnfinal_k<<<1, 256, 0, stream>>>(st, g3, be3, ss, invN);
    bnelu_k<true><<<bg4, 256, 0, stream>>>(out, ss, hn, t4);

    // ---- GAT layer 1 ----
    gemm_k<false, true><<<gb, 256, 0, stream>>>(hn, Wg1T, xl, N, 256, 256, 256, 4);
    adot_k<<<(N + 3) / 4, 256, 0, stream>>>(xl, as1, ad1, a_src, a_dst, N);
    gat_k<<<(N + 3) / 4, 256, 0, stream>>>(xl, a_src, a_dst, csr, indptr, out, N);
    hipMemsetAsync(st, 0, 2048, stream);
    colstats_k<<<1024, 256, 0, stream>>>(out, st, t4);
    bnfinal_k<<<1, 256, 0, stream>>>(st, g4, be4, ss, invN);
    bnelu_k<true><<<bg4, 256, 0, stream>>>(out, ss, hn, t4);

    // ---- GAT layer 2 ----
    gemm_k<false, true><<<gb, 256, 0, stream>>>(hn, Wg2T, xl, N, 256, 256, 256, 4);
    adot_k<<<(N + 3) / 4, 256, 0, stream>>>(xl, as2, ad2, a_src, a_dst, N);
    gat_k<<<(N + 3) / 4, 256, 0, stream>>>(xl, a_src, a_dst, csr, indptr, out, N);
    hipMemsetAsync(st, 0, 2048, stream);
    colstats_k<<<1024, 256, 0, stream>>>(out, st, t4);
    bnfinal_k<<<1, 256, 0, stream>>>(st, g5, be5, ss, invN);
    bnelu_k<false><<<bg4, 256, 0, stream>>>(out, ss, out, t4);  // final, in-place f32
}

// Round 3
// 1153.524 us; speedup vs baseline: 1.2477x; 1.1561x over previous
//
#include <hip/hip_runtime.h>

#define DEV __device__ __forceinline__

typedef __attribute__((ext_vector_type(4))) float f32x4;
typedef __attribute__((ext_vector_type(8))) short short8;

DEV float bf2f(unsigned short u) {
    union { unsigned int i; float f; } c;
    c.i = ((unsigned int)u) << 16;
    return c.f;
}
DEV unsigned short f2bf(float f) {
    union { float f; unsigned int i; } c;
    c.f = f;
    unsigned int u = c.i;
    u += 0x7FFFu + ((u >> 16) & 1u);   // RTNE (finite values only here)
    return (unsigned short)(u >> 16);
}

// ---------------------------------------------------------------------------
// GEMM: C[M,256] = A[M,K] @ B[K,256], B pre-transposed+bf16 as Bt[256][ldb].
// BM=64, BN=256, BK=64, 256 threads (4 waves, each owns a 64x64 C tile).
// Depth-2 counted-vmcnt pipeline (T3+T4): raw s_barrier, s_waitcnt vmcnt(N),
// loads of tile k+1 stay in flight across the whole of tile k's compute.
// Per-wave vmem ops per tile: bf16 A path = 10 (2 A + 8 B global_load_lds);
// f32 A path = 12 (4 reg dwordx4 + 8 B). Load counts are UNIFORM per wave
// (clamped addresses; k>=Kreal columns hit zero-padded B rows -> contribute 0,
// m>=M rows are never stored and masked out of stats).
// LDS layout [row][chunk] with chunk XOR-swizzle (c ^= row&7), chunk = 8 bf16.
// ---------------------------------------------------------------------------
template<bool A_F32, bool OUT_BF16, bool STATS>
__launch_bounds__(256)
__global__ void gemm_k(const void* __restrict__ Aptr,
                       const unsigned short* __restrict__ Bt,
                       void* __restrict__ Cptr,
                       float* __restrict__ st,
                       int M, int lda, int ldb, int ksteps)
{
    __shared__ __align__(16) unsigned short As[2][64 * 64];
    __shared__ __align__(16) unsigned short Bs[2][256 * 64];
    const int t    = threadIdx.x;
    const int wid  = t >> 6;
    const int lane = t & 63;
    const int m0   = blockIdx.x * 64;

    const float* Af          = (const float*)Aptr;
    const unsigned short* Ab = (const unsigned short*)Aptr;
    const size_t maxoff = (size_t)M * (size_t)lda - 4;   // f32 clamp bound

    f32x4 acc[4][4] = {};
    float ar0[16], ar1[16];    // f32-A double reg-staging (static indexing)

    auto stageB = [&](int buf, int ks) {
        const int k0 = ks * 64;
        #pragma unroll
        for (int is = 0; is < 8; ++is) {
            const int rbase = wid * 64 + is * 8;
            const int rr  = rbase + (lane >> 3);
            const int csw = (lane & 7) ^ (rr & 7);         // pre-swizzled source
            __builtin_amdgcn_global_load_lds(
                (const __attribute__((address_space(1))) void*)(Bt + (size_t)rr * ldb + k0 + csw * 8),
                (__attribute__((address_space(3))) void*)(&Bs[buf][rbase * 64]),
                16, 0, 0);
        }
    };
    auto stageAb = [&](int buf, int ks) {
        const int k0 = ks * 64;
        #pragma unroll
        for (int is = 0; is < 2; ++is) {
            const int rbase = wid * 16 + is * 8;
            const int rr  = rbase + (lane >> 3);
            const int csw = (lane & 7) ^ (rr & 7);
            __builtin_amdgcn_global_load_lds(
                (const __attribute__((address_space(1))) void*)(Ab + (size_t)(m0 + rr) * lda + k0 + csw * 8),
                (__attribute__((address_space(3))) void*)(&As[buf][rbase * 64]),
                16, 0, 0);
        }
    };
    auto loadAf = [&](int ks, float (&ar)[16]) {   // 4 uniform dwordx4 per wave
        const int k0 = ks * 64;
        #pragma unroll
        for (int i = 0; i < 4; ++i) {
            const int tt  = t + i * 256;
            const int row = tt >> 4;            // 0..63
            const int cg  = tt & 15;            // 4-float column group
            size_t off = (size_t)(m0 + row) * lda + (k0 + cg * 4);
            off = off < maxoff ? off : maxoff;  // clamp: garbage x zero-B = 0
            *(f32x4*)&ar[i * 4] = *(const f32x4*)(Af + off);
        }
    };
    auto writeAf = [&](int buf, float (&ar)[16]) {  // cvt + swizzled ds_write_b64
        #pragma unroll
        for (int i = 0; i < 4; ++i) {
            const int tt  = t + i * 256;
            const int row = tt >> 4;
            const int cg  = tt & 15;
            uint2 pk;
            pk.x = (unsigned int)f2bf(ar[i * 4 + 0]) | ((unsigned int)f2bf(ar[i * 4 + 1]) << 16);
            pk.y = (unsigned int)f2bf(ar[i * 4 + 2]) | ((unsigned int)f2bf(ar[i * 4 + 3]) << 16);
            *(uint2*)&As[buf][row * 64 + ((((cg >> 1) ^ (row & 7)) << 3) | ((cg & 1) << 2))] = pk;
        }
    };
    auto compute = [&](int buf) {
        #pragma unroll
        for (int kk = 0; kk < 2; ++kk) {
            short8 af[4], bfr[4];
            #pragma unroll
            for (int mi = 0; mi < 4; ++mi) {
                const int r   = mi * 16 + (lane & 15);
                const int csw = (kk * 4 + (lane >> 4)) ^ (r & 7);
                af[mi] = *(const short8*)(&As[buf][r * 64 + csw * 8]);
            }
            #pragma unroll
            for (int ni = 0; ni < 4; ++ni) {
                const int r   = wid * 64 + ni * 16 + (lane & 15);
                const int csw = (kk * 4 + (lane >> 4)) ^ (r & 7);
                bfr[ni] = *(const short8*)(&Bs[buf][r * 64 + csw * 8]);
            }
            #pragma unroll
            for (int mi = 0; mi < 4; ++mi)
                #pragma unroll
                for (int ni = 0; ni < 4; ++ni)
                    acc[mi][ni] = __builtin_amdgcn_mfma_f32_16x16x32_bf16(
                        af[mi], bfr[ni], acc[mi][ni], 0, 0, 0);
        }
    };

    // ---- prologue: tiles 0 and 1 in flight ----
    if constexpr (A_F32) loadAf(0, ar0); else stageAb(0, 0);
    stageB(0, 0);
    __builtin_amdgcn_sched_barrier(0);          // keep tile groups separate
    if constexpr (A_F32) loadAf(1, ar1); else stageAb(1, 1);
    stageB(1, 1);
    if constexpr (A_F32) {
        asm volatile("s_waitcnt vmcnt(12)" ::: "memory");   // tile 0 loads done
        __builtin_amdgcn_sched_barrier(0);
        writeAf(0, ar0);
        asm volatile("s_waitcnt lgkmcnt(0)" ::: "memory");
    } else {
        asm volatile("s_waitcnt vmcnt(10)" ::: "memory");
    }
    __builtin_amdgcn_sched_barrier(0);
    __builtin_amdgcn_s_barrier();
    __builtin_amdgcn_sched_barrier(0);

    // ---- main loop ----
    int cur = 0;
    for (int k = 0; k < ksteps; ++k) {
        compute(cur);                            // tile k from buf[cur]
        if (k + 1 >= ksteps) break;
        __builtin_amdgcn_sched_barrier(0);
        __builtin_amdgcn_s_barrier();            // buf[cur] free for overwrite
        __builtin_amdgcn_sched_barrier(0);
        if (k + 2 < ksteps) {
            if constexpr (A_F32) {
                if (k & 1) loadAf(k + 2, ar1); else loadAf(k + 2, ar0);
            } else {
                stageAb(cur, k + 2);
            }
            stageB(cur, k + 2);
            if constexpr (A_F32)
                asm volatile("s_waitcnt vmcnt(12)" ::: "memory");  // tile k+1 done
            else
                asm volatile("s_waitcnt vmcnt(10)" ::: "memory");
        } else {
            asm volatile("s_waitcnt vmcnt(0)" ::: "memory");
        }
        __builtin_amdgcn_sched_barrier(0);
        if constexpr (A_F32) {                   // A(k+1) regs -> As[cur^1]
            if (k & 1) writeAf(cur ^ 1, ar0); else writeAf(cur ^ 1, ar1);
            asm volatile("s_waitcnt lgkmcnt(0)" ::: "memory");
            __builtin_amdgcn_sched_barrier(0);
        }
        __builtin_amdgcn_s_barrier();            // buf[cur^1] ready
        __builtin_amdgcn_sched_barrier(0);
        cur ^= 1;
    }

    // ---- epilogue: C col = lane&15, row = (lane>>4)*4 + reg ----
    #pragma unroll
    for (int mi = 0; mi < 4; ++mi) {
        #pragma unroll
        for (int ni = 0; ni < 4; ++ni) {
            const int col = wid * 64 + ni * 16 + (lane & 15);
            #pragma unroll
            for (int rg = 0; rg < 4; ++rg) {
                const int m = m0 + mi * 16 + (lane >> 4) * 4 + rg;
                if (m < M) {
                    if constexpr (OUT_BF16)
                        ((unsigned short*)Cptr)[(size_t)m * 256 + col] = f2bf(acc[mi][ni][rg]);
                    else
                        ((float*)Cptr)[(size_t)m * 256 + col] = acc[mi][ni][rg];
                }
            }
        }
    }
    if constexpr (STATS) {    // fused BN column stats (sum, sumsq)
        #pragma unroll
        for (int ni = 0; ni < 4; ++ni) {
            float s = 0.f, q = 0.f;
            #pragma unroll
            for (int mi = 0; mi < 4; ++mi)
                #pragma unroll
                for (int rg = 0; rg < 4; ++rg) {
                    const int m = m0 + mi * 16 + (lane >> 4) * 4 + rg;
                    const float v = (m < M) ? acc[mi][ni][rg] : 0.f;
                    s += v; q += v * v;
                }
            s += __shfl_xor(s, 16); q += __shfl_xor(q, 16);
            s += __shfl_xor(s, 32); q += __shfl_xor(q, 32);
            if (lane < 16) {
                const int col = wid * 64 + ni * 16 + lane;
                atomicAdd(&st[col], s);
                atomicAdd(&st[256 + col], q);
            }
        }
    }
}

// W[K,256] f32 -> WT[256][ldb] bf16 transposed, zero-padded k >= K.
__global__ void wtrans_k(const float* __restrict__ W, unsigned short* __restrict__ WT,
                         int K, int ldb) {
    int total = 256 * ldb;
    for (int idx = blockIdx.x * blockDim.x + threadIdx.x; idx < total;
         idx += gridDim.x * blockDim.x) {
        int n = idx / ldb, k = idx - n * ldb;
        WT[idx] = f2bf(k < K ? W[(size_t)k * 256 + n] : 0.f);
    }
}

// per-column sum & sum-of-squares into st[0..255], st[256..511] (GAT outputs).
__global__ void colstats_k(const float* __restrict__ h, float* st, int total4) {
    const int gid    = blockIdx.x * 256 + threadIdx.x;
    const int stride = gridDim.x * 256;
    float4 s = {0.f, 0.f, 0.f, 0.f}, q = {0.f, 0.f, 0.f, 0.f};
    for (int i = gid; i < total4; i += stride) {
        float4 v = ((const float4*)h)[i];
        s.x += v.x; s.y += v.y; s.z += v.z; s.w += v.w;
        q.x += v.x * v.x; q.y += v.y * v.y; q.z += v.z * v.z; q.w += v.w * v.w;
    }
    __shared__ float red[2][4][64][4];
    const int wid = threadIdx.x >> 6, lane = threadIdx.x & 63;
    *(float4*)&red[0][wid][lane][0] = s;
    *(float4*)&red[1][wid][lane][0] = q;
    __syncthreads();
    if (wid == 0) {
        float4 s0 = *(float4*)&red[0][0][lane][0];
        float4 q0 = *(float4*)&red[1][0][lane][0];
        #pragma unroll
        for (int w = 1; w < 4; ++w) {
            float4 sw = *(float4*)&red[0][w][lane][0];
            float4 qw = *(float4*)&red[1][w][lane][0];
            s0.x += sw.x; s0.y += sw.y; s0.z += sw.z; s0.w += sw.w;
            q0.x += qw.x; q0.y += qw.y; q0.z += qw.z; q0.w += qw.w;
        }
        atomicAdd(&st[lane * 4 + 0], s0.x);
        atomicAdd(&st[lane * 4 + 1], s0.y);
        atomicAdd(&st[lane * 4 + 2], s0.z);
        atomicAdd(&st[lane * 4 + 3], s0.w);
        atomicAdd(&st[256 + lane * 4 + 0], q0.x);
        atomicAdd(&st[256 + lane * 4 + 1], q0.y);
        atomicAdd(&st[256 + lane * 4 + 2], q0.z);
        atomicAdd(&st[256 + lane * 4 + 3], q0.w);
    }
}

__global__ void bnfinal_k(const float* __restrict__ st, const float* __restrict__ g,
                          const float* __restrict__ be, float* __restrict__ ss, float invN) {
    int c = threadIdx.x;
    float mu  = st[c] * invN;
    float var = st[256 + c] * invN - mu * mu;
    float sc  = g[c] * rsqrtf(var + 1e-5f);
    ss[c]       = sc;
    ss[256 + c] = be[c] - mu * sc;
}

// y = elu(scale*v + shift); OUT_BF16 -> bf16 buffer, else f32 (may alias input)
template<bool OUT_BF16>
__global__ void bnelu_k(const float* h, const float* ss, void* outp, int total4) {
    for (int i = blockIdx.x * blockDim.x + threadIdx.x; i < total4;
         i += gridDim.x * blockDim.x) {
        float4 v = ((const float4*)h)[i];
        int c = (i << 2) & 255;
        float4 y;
        y.x = fmaf(v.x, ss[c + 0], ss[256 + c + 0]);
        y.y = fmaf(v.y, ss[c + 1], ss[256 + c + 1]);
        y.z = fmaf(v.z, ss[c + 2], ss[256 + c + 2]);
        y.w = fmaf(v.w, ss[c + 3], ss[256 + c + 3]);
        y.x = y.x > 0.f ? y.x : expm1f(y.x);
        y.y = y.y > 0.f ? y.y : expm1f(y.y);
        y.z = y.z > 0.f ? y.z : expm1f(y.z);
        y.w = y.w > 0.f ? y.w : expm1f(y.w);
        if (OUT_BF16) {
            ushort4 o;
            o.x = f2bf(y.x); o.y = f2bf(y.y); o.z = f2bf(y.z); o.w = f2bf(y.w);
            ((ushort4*)outp)[i] = o;
        } else {
            ((float4*)outp)[i] = y;
        }
    }
}

// per-row dot products with att vectors (wave per row)
__global__ void adot_k(const unsigned short* __restrict__ xl, const float* __restrict__ as_,
                       const float* __restrict__ ad_, float* __restrict__ a_src,
                       float* __restrict__ a_dst, int N) {
    int w = (blockIdx.x * blockDim.x + threadIdx.x) >> 6;
    int lane = threadIdx.x & 63;
    if (w >= N) return;
    ushort4 v = *(const ushort4*)(xl + (size_t)w * 256 + lane * 4);
    float4 s4 = *(const float4*)(as_ + lane * 4);
    float4 d4 = *(const float4*)(ad_ + lane * 4);
    float x0 = bf2f(v.x), x1 = bf2f(v.y), x2 = bf2f(v.z), x3 = bf2f(v.w);
    float ps = x0 * s4.x + x1 * s4.y + x2 * s4.z + x3 * s4.w;
    float pd = x0 * d4.x + x1 * d4.y + x2 * d4.z + x3 * d4.w;
    #pragma unroll
    for (int off = 32; off; off >>= 1) {
        ps += __shfl_xor(ps, off);
        pd += __shfl_xor(pd, off);
    }
    if (lane == 0) { a_src[w] = ps; a_dst[w] = pd; }
}

// one wave per destination node: softmax over incoming edges + weighted gather
__global__ void gat_k(const unsigned short* __restrict__ xl, const float* __restrict__ a_src,
                      const float* __restrict__ a_dst, const int* __restrict__ csr,
                      const int* __restrict__ indptr, float* __restrict__ out, int N) {
    int d = (blockIdx.x * blockDim.x + threadIdx.x) >> 6;
    int lane = threadIdx.x & 63;
    if (d >= N) return;
    int beg = indptr[d], end = indptr[d + 1];
    float adst = a_dst[d];
    float mx = -1e30f;
    for (int i = beg + lane; i < end; i += 64) {
        float e = a_src[csr[i]] + adst;
        e = e > 0.f ? e : 0.2f * e;
        mx = fmaxf(mx, e);
    }
    #pragma unroll
    for (int off = 32; off; off >>= 1) mx = fmaxf(mx, __shfl_xor(mx, off));
    float sm = 0.f;
    for (int i = beg + lane; i < end; i += 64) {
        float e = a_src[csr[i]] + adst;
        e = e > 0.f ? e : 0.2f * e;
        sm += __expf(e - mx);
    }
    #pragma unroll
    for (int off = 32; off; off >>= 1) sm += __shfl_xor(sm, off);
    float inv = 1.f / (sm + 1e-16f);
    float4 acc = {0.f, 0.f, 0.f, 0.f};
    for (int i = beg; i < end; ++i) {
        int s = csr[i];                       // uniform across wave
        float e = a_src[s] + adst;
        e = e > 0.f ? e : 0.2f * e;
        float al = __expf(e - mx) * inv;
        ushort4 v = *(const ushort4*)(xl + (size_t)s * 256 + lane * 4);
        acc.x += al * bf2f(v.x);
        acc.y += al * bf2f(v.y);
        acc.z += al * bf2f(v.z);
        acc.w += al * bf2f(v.w);
    }
    *(float4*)(out + (size_t)d * 256 + lane * 4) = acc;
}

// ---- CSR build ----
__global__ void hist_k(const int* __restrict__ edges, int* deg, int E, int N) {
    int total = E + N;
    for (int i = blockIdx.x * blockDim.x + threadIdx.x; i < total;
         i += gridDim.x * blockDim.x) {
        int dd = (i < E) ? edges[E + i] : (i - E);
        atomicAdd(&deg[dd], 1);
    }
}

__global__ void scan1_k(const int* __restrict__ deg, int* iscan, int* bsum, int N) {
    int i = blockIdx.x * 256 + threadIdx.x;
    int lane = threadIdx.x & 63, wid = threadIdx.x >> 6;
    int v = (i < N) ? deg[i] : 0;
    #pragma unroll
    for (int off = 1; off < 64; off <<= 1) {
        int u = __shfl_up(v, off);
        if (lane >= off) v += u;
    }
    __shared__ int wsum[4];
    if (lane == 63) wsum[wid] = v;
    __syncthreads();
    #pragma unroll
    for (int w = 0; w < 3; ++w) if (wid > w) v += wsum[w];
    if (i < N) iscan[i] = v;
    if (threadIdx.x == 255) bsum[blockIdx.x] = v;
}

__global__ void scan2_k(int* bsum, int nb) {   // nb <= 256
    int t = threadIdx.x;
    int lane = t & 63, wid = t >> 6;
    int v = (t < nb) ? bsum[t] : 0;
    int orig = v;
    #pragma unroll
    for (int off = 1; off < 64; off <<= 1) {
        int u = __shfl_up(v, off);
        if (lane >= off) v += u;
    }
    __shared__ int wsum[4];
    if (lane == 63) wsum[wid] = v;
    __syncthreads();
    #pragma unroll
    for (int w = 0; w < 3; ++w) if (wid > w) v += wsum[w];
    if (t < nb) bsum[t] = v - orig;            // exclusive block offsets
}

__global__ void scan3_k(const int* __restrict__ iscan, const int* __restrict__ boff,
                        int* indptr, int N) {
    int i = blockIdx.x * 256 + threadIdx.x;
    if (i < N) indptr[i + 1] = iscan[i] + boff[blockIdx.x];
    if (i == 0) indptr[0] = 0;
}

__global__ void copy_k(const int* __restrict__ a, int* b, int N) {
    for (int i = blockIdx.x * blockDim.x + threadIdx.x; i < N;
         i += gridDim.x * blockDim.x) b[i] = a[i];
}

__global__ void scatter_k(const int* __restrict__ edges, int* pos, int* csr, int E, int N) {
    int total = E + N;
    for (int i = blockIdx.x * blockDim.x + threadIdx.x; i < total;
         i += gridDim.x * blockDim.x) {
        int s  = (i < E) ? edges[i]     : (i - E);
        int dd = (i < E) ? edges[E + i] : (i - E);
        int slot = atomicAdd(&pos[dd], 1);
        csr[slot] = s;
    }
}

// ---------------------------------------------------------------------------
extern "C" void kernel_launch(void* const* d_in, const int* in_sizes, int n_in,
                              void* d_out, int out_size, void* d_ws, size_t ws_size,
                              hipStream_t stream) {
    const float* x     = (const float*)d_in[0];
    const int*   edges = (const int*)d_in[1];
    const float* W1 = (const float*)d_in[2];
    const float* W2 = (const float*)d_in[4];
    const float* W3 = (const float*)d_in[6];
    const float* g1 = (const float*)d_in[8],  *be1 = (const float*)d_in[9];
    const float* g2 = (const float*)d_in[10], *be2 = (const float*)d_in[11];
    const float* g3 = (const float*)d_in[12], *be3 = (const float*)d_in[13];
    const float* Wg1 = (const float*)d_in[14];
    const float* as1 = (const float*)d_in[15], *ad1 = (const float*)d_in[16];
    const float* g4 = (const float*)d_in[18], *be4 = (const float*)d_in[19];
    const float* Wg2 = (const float*)d_in[20];
    const float* as2 = (const float*)d_in[21], *ad2 = (const float*)d_in[22];
    const float* g5 = (const float*)d_in[24], *be5 = (const float*)d_in[25];

    const int N    = out_size / 256;
    const int K1   = in_sizes[0] / N;
    const int E    = in_sizes[1] / 2;
    const int Etot = E + N;
    const int ks1  = (K1 + 63) / 64;
    const int ldb1 = ks1 * 64;

    // workspace carve (256B aligned)
    char* p = (char*)d_ws;
    auto alloc = [&](size_t bytes) {
        char* r = p;
        p += (bytes + 255) & ~(size_t)255;
        return r;
    };
    unsigned short* W1T  = (unsigned short*)alloc((size_t)256 * ldb1 * 2);
    unsigned short* W2T  = (unsigned short*)alloc(256 * 256 * 2);
    unsigned short* W3T  = (unsigned short*)alloc(256 * 256 * 2);
    unsigned short* Wg1T = (unsigned short*)alloc(256 * 256 * 2);
    unsigned short* Wg2T = (unsigned short*)alloc(256 * 256 * 2);
    unsigned short* hn   = (unsigned short*)alloc((size_t)N * 256 * 2);
    unsigned short* xl   = (unsigned short*)alloc((size_t)N * 256 * 2);
    float* a_src  = (float*)alloc((size_t)N * 4);
    float* a_dst  = (float*)alloc((size_t)N * 4);
    int*   deg    = (int*)alloc((size_t)N * 4);
    int*   iscan  = (int*)alloc((size_t)N * 4);
    int*   bsum   = (int*)alloc(1024);
    int*   indptr = (int*)alloc((size_t)(N + 1) * 4);
    int*   pos    = (int*)alloc((size_t)N * 4);
    int*   csr    = (int*)alloc((size_t)Etot * 4);
    float* st     = (float*)alloc(512 * 4);
    float* ss     = (float*)alloc(512 * 4);
    (void)alloc(65536); // tail guard for benign over-reads
    float* out = (float*)d_out;

    const int nb = (N + 255) / 256;
    const int eg = (Etot + 255) / 256;
    const int gb = (N + 63) / 64;
    const int t4 = N * 64;                    // (N*256)/4
    const int bg4 = (t4 + 255) / 256;

    // ---- graph CSR (shared by both GAT layers) ----
    hipMemsetAsync(deg, 0, (size_t)N * 4, stream);
    hist_k<<<eg, 256, 0, stream>>>(edges, deg, E, N);
    scan1_k<<<nb, 256, 0, stream>>>(deg, iscan, bsum, N);
    scan2_k<<<1, 256, 0, stream>>>(bsum, nb);
    scan3_k<<<nb, 256, 0, stream>>>(iscan, bsum, indptr, N);
    copy_k<<<nb, 256, 0, stream>>>(indptr, pos, N);
    scatter_k<<<eg, 256, 0, stream>>>(edges, pos, csr, E, N);

    // ---- weight prep (transpose + bf16) ----
    wtrans_k<<<(256 * ldb1 + 255) / 256, 256, 0, stream>>>(W1, W1T, K1, ldb1);
    wtrans_k<<<256, 256, 0, stream>>>(W2, W2T, 256, 256);
    wtrans_k<<<256, 256, 0, stream>>>(W3, W3T, 256, 256);
    wtrans_k<<<256, 256, 0, stream>>>(Wg1, Wg1T, 256, 256);
    wtrans_k<<<256, 256, 0, stream>>>(Wg2, Wg2T, 256, 256);

    const float invN = 1.f / (float)N;

    // ---- layer 1: x @ W1 -> BN -> ELU (bias cancels in BN; stats fused) ----
    hipMemsetAsync(st, 0, 2048, stream);
    gemm_k<true, false, true><<<gb, 256, 0, stream>>>(x, W1T, out, st, N, K1, ldb1, ks1);
    bnfinal_k<<<1, 256, 0, stream>>>(st, g1, be1, ss, invN);
    bnelu_k<true><<<bg4, 256, 0, stream>>>(out, ss, hn, t4);

    // ---- layer 2 ----
    hipMemsetAsync(st, 0, 2048, stream);
    gemm_k<false, false, true><<<gb, 256, 0, stream>>>(hn, W2T, out, st, N, 256, 256, 4);
    bnfinal_k<<<1, 256, 0, stream>>>(st, g2, be2, ss, invN);
    bnelu_k<true><<<bg4, 256, 0, stream>>>(out, ss, hn, t4);

    // ---- layer 3 ----
    hipMemsetAsync(st, 0, 2048, stream);
    gemm_k<false, false, true><<<gb, 256, 0, stream>>>(hn, W3T, out, st, N, 256, 256, 4);
    bnfinal_k<<<1, 256, 0, stream>>>(st, g3, be3, ss, invN);
    bnelu_k<true><<<bg4, 256, 0, stream>>>(out, ss, hn, t4);

    // ---- GAT layer 1 ----
    gemm_k<false, true, false><<<gb, 256, 0, stream>>>(hn, Wg1T, xl, st, N, 256, 256, 4);
    adot_k<<<(N + 3) / 4, 256, 0, stream>>>(xl, as1, ad1, a_src, a_dst, N);
    gat_k<<<(N + 3) / 4, 256, 0, stream>>>(xl, a_src, a_dst, csr, indptr, out, N);
    hipMemsetAsync(st, 0, 2048, stream);
    colstats_k<<<1024, 256, 0, stream>>>(out, st, t4);
    bnfinal_k<<<1, 256, 0, stream>>>(st, g4, be4, ss, invN);
    bnelu_k<true><<<bg4, 256, 0, stream>>>(out, ss, hn, t4);

    // ---- GAT layer 2 ----
    gemm_k<false, true, false><<<gb, 256, 0, stream>>>(hn, Wg2T, xl, st, N, 256, 256, 4);
    adot_k<<<(N + 3) / 4, 256, 0, stream>>>(xl, as2, ad2, a_src, a_dst, N);
    gat_k<<<(N + 3) / 4, 256, 0, stream>>>(xl, a_src, a_dst, csr, indptr, out, N);
    hipMemsetAsync(st, 0, 2048, stream);
    colstats_k<<<1024, 256, 0, stream>>>(out, st, t4);
    bnfinal_k<<<1, 256, 0, stream>>>(st, g5, be5, ss, invN);
    bnelu_k<false><<<bg4, 256, 0, stream>>>(out, ss, out, t4);  // final, in-place f32
}

// Round 4
// 1025.966 us; speedup vs baseline: 1.4028x; 1.1243x over previous
//
#include <hip/hip_runtime.h>

#define DEV __device__ __forceinline__

typedef __attribute__((ext_vector_type(4))) float f32x4;
typedef __attribute__((ext_vector_type(8))) short short8;

DEV float bf2f(unsigned short u) {
    union { unsigned int i; float f; } c;
    c.i = ((unsigned int)u) << 16;
    return c.f;
}
DEV unsigned short f2bf(float f) {
    union { float f; unsigned int i; } c;
    c.f = f;
    unsigned int u = c.i;
    u += 0x7FFFu + ((u >> 16) & 1u);   // RTNE (finite values only here)
    return (unsigned short)(u >> 16);
}

// ---------------------------------------------------------------------------
// GEMM: C[M,256] = A[M,K] @ B[K,256], B pre-transposed+bf16 as Bt[256][ldb].
// BM=128, BN=256, BK=64, 512 threads = 8 waves (2 row-bands x 4 col-bands),
// each wave owns a 64x64 C tile (acc 4x4 f32x4).
// Depth-2 counted-vmcnt pipeline: per-wave vmem ops per tile:
//   f32 A path: 8  (4 reg dwordx4 + 4 B global_load_lds)  -> vmcnt(8)
//   bf16 A path: 6 (2 A global_load_lds + 4 B)            -> vmcnt(6)
// Per k-step HBM volume (32KB A-f32) >> latency, so stalls amortize.
// Requires ksteps >= 2 (true: 4 and 41).
// LDS [row][chunk] with chunk XOR-swizzle (c ^= row&7), chunk = 8 bf16.
// ---------------------------------------------------------------------------
template<bool A_F32, bool OUT_BF16, bool STATS>
__launch_bounds__(512)
__global__ void gemm_k(const void* __restrict__ Aptr,
                       const unsigned short* __restrict__ Bt,
                       void* __restrict__ Cptr,
                       float* __restrict__ st,
                       int M, int lda, int ldb, int ksteps)
{
    __shared__ __align__(16) unsigned short As[2][128 * 64];
    __shared__ __align__(16) unsigned short Bs[2][256 * 64];
    const int t    = threadIdx.x;
    const int wid  = t >> 6;       // 0..7
    const int lane = t & 63;
    const int wr   = wid >> 2;     // 0..1  (64-row band)
    const int wc   = wid & 3;      // 0..3  (64-col band)
    const int m0   = blockIdx.x * 128;

    const float* Af          = (const float*)Aptr;
    const unsigned short* Ab = (const unsigned short*)Aptr;
    const size_t maxoff = (size_t)M * (size_t)lda - 4;   // f32 clamp bound

    f32x4 acc[4][4] = {};
    float ar0[16], ar1[16];    // f32-A double reg-staging (static indexing)

    auto stageB = [&](int buf, int ks) {       // 4 global_load_lds per wave
        const int k0 = ks * 64;
        #pragma unroll
        for (int is = 0; is < 4; ++is) {
            const int rbase = wid * 32 + is * 8;
            const int rr  = rbase + (lane >> 3);
            const int csw = (lane & 7) ^ (rr & 7);         // pre-swizzled source
            __builtin_amdgcn_global_load_lds(
                (const __attribute__((address_space(1))) void*)(Bt + (size_t)rr * ldb + k0 + csw * 8),
                (__attribute__((address_space(3))) void*)(&Bs[buf][rbase * 64]),
                16, 0, 0);
        }
    };
    auto stageAb = [&](int buf, int ks) {      // 2 global_load_lds per wave
        const int k0 = ks * 64;
        #pragma unroll
        for (int is = 0; is < 2; ++is) {
            const int rbase = wid * 16 + is * 8;
            const int rr  = rbase + (lane >> 3);
            const int csw = (lane & 7) ^ (rr & 7);
            __builtin_amdgcn_global_load_lds(
                (const __attribute__((address_space(1))) void*)(Ab + (size_t)(m0 + rr) * lda + k0 + csw * 8),
                (__attribute__((address_space(3))) void*)(&As[buf][rbase * 64]),
                16, 0, 0);
        }
    };
    auto loadAf = [&](int ks, float (&ar)[16]) {   // 4 uniform dwordx4 per thread
        const int k0 = ks * 64;
        #pragma unroll
        for (int i = 0; i < 4; ++i) {
            const int tt  = t + i * 512;
            const int row = tt >> 4;            // 0..127
            const int cg  = tt & 15;            // 4-float column group
            size_t off = (size_t)(m0 + row) * lda + (k0 + cg * 4);
            off = off < maxoff ? off : maxoff;  // clamp: garbage x zero-B = 0
            *(f32x4*)&ar[i * 4] = *(const f32x4*)(Af + off);
        }
    };
    auto writeAf = [&](int buf, float (&ar)[16]) {  // cvt + swizzled ds_write_b64
        #pragma unroll
        for (int i = 0; i < 4; ++i) {
            const int tt  = t + i * 512;
            const int row = tt >> 4;
            const int cg  = tt & 15;
            uint2 pk;
            pk.x = (unsigned int)f2bf(ar[i * 4 + 0]) | ((unsigned int)f2bf(ar[i * 4 + 1]) << 16);
            pk.y = (unsigned int)f2bf(ar[i * 4 + 2]) | ((unsigned int)f2bf(ar[i * 4 + 3]) << 16);
            *(uint2*)&As[buf][row * 64 + ((((cg >> 1) ^ (row & 7)) << 3) | ((cg & 1) << 2))] = pk;
        }
    };
    auto compute = [&](int buf) {
        #pragma unroll
        for (int kk = 0; kk < 2; ++kk) {
            short8 af[4], bfr[4];
            #pragma unroll
            for (int mi = 0; mi < 4; ++mi) {
                const int r   = wr * 64 + mi * 16 + (lane & 15);
                const int csw = (kk * 4 + (lane >> 4)) ^ (r & 7);
                af[mi] = *(const short8*)(&As[buf][r * 64 + csw * 8]);
            }
            #pragma unroll
            for (int ni = 0; ni < 4; ++ni) {
                const int r   = wc * 64 + ni * 16 + (lane & 15);
                const int csw = (kk * 4 + (lane >> 4)) ^ (r & 7);
                bfr[ni] = *(const short8*)(&Bs[buf][r * 64 + csw * 8]);
            }
            #pragma unroll
            for (int mi = 0; mi < 4; ++mi)
                #pragma unroll
                for (int ni = 0; ni < 4; ++ni)
                    acc[mi][ni] = __builtin_amdgcn_mfma_f32_16x16x32_bf16(
                        af[mi], bfr[ni], acc[mi][ni], 0, 0, 0);
        }
    };

    // ---- prologue: tiles 0 and 1 in flight ----
    if constexpr (A_F32) loadAf(0, ar0); else stageAb(0, 0);
    stageB(0, 0);
    __builtin_amdgcn_sched_barrier(0);
    if constexpr (A_F32) loadAf(1, ar1); else stageAb(1, 1);
    stageB(1, 1);
    if constexpr (A_F32) {
        asm volatile("s_waitcnt vmcnt(8)" ::: "memory");    // tile 0 fully done
        __builtin_amdgcn_sched_barrier(0);
        writeAf(0, ar0);
        asm volatile("s_waitcnt lgkmcnt(0)" ::: "memory");
    } else {
        asm volatile("s_waitcnt vmcnt(6)" ::: "memory");
    }
    __builtin_amdgcn_sched_barrier(0);
    __builtin_amdgcn_s_barrier();
    __builtin_amdgcn_sched_barrier(0);

    // ---- main loop ----
    int cur = 0;
    for (int k = 0; k < ksteps; ++k) {
        compute(cur);                            // tile k from buf[cur]
        if (k + 1 >= ksteps) break;
        __builtin_amdgcn_sched_barrier(0);
        __builtin_amdgcn_s_barrier();            // buf[cur] free for overwrite
        __builtin_amdgcn_sched_barrier(0);
        if (k + 2 < ksteps) {
            if constexpr (A_F32) {
                if (k & 1) loadAf(k + 2, ar1); else loadAf(k + 2, ar0);
            } else {
                stageAb(cur, k + 2);
            }
            stageB(cur, k + 2);
            if constexpr (A_F32)
                asm volatile("s_waitcnt vmcnt(8)" ::: "memory");  // tile k+1 done
            else
                asm volatile("s_waitcnt vmcnt(6)" ::: "memory");
        } else {
            asm volatile("s_waitcnt vmcnt(0)" ::: "memory");
        }
        __builtin_amdgcn_sched_barrier(0);
        if constexpr (A_F32) {                   // A(k+1) regs -> As[cur^1]
            if (k & 1) writeAf(cur ^ 1, ar0); else writeAf(cur ^ 1, ar1);
            asm volatile("s_waitcnt lgkmcnt(0)" ::: "memory");
            __builtin_amdgcn_sched_barrier(0);
        }
        __builtin_amdgcn_s_barrier();            // buf[cur^1] ready
        __builtin_amdgcn_sched_barrier(0);
        cur ^= 1;
    }

    // ---- epilogue: C col = lane&15, row = (lane>>4)*4 + reg ----
    #pragma unroll
    for (int mi = 0; mi < 4; ++mi) {
        #pragma unroll
        for (int ni = 0; ni < 4; ++ni) {
            const int col = wc * 64 + ni * 16 + (lane & 15);
            #pragma unroll
            for (int rg = 0; rg < 4; ++rg) {
                const int m = m0 + wr * 64 + mi * 16 + (lane >> 4) * 4 + rg;
                if (m < M) {
                    if constexpr (OUT_BF16)
                        ((unsigned short*)Cptr)[(size_t)m * 256 + col] = f2bf(acc[mi][ni][rg]);
                    else
                        ((float*)Cptr)[(size_t)m * 256 + col] = acc[mi][ni][rg];
                }
            }
        }
    }
    if constexpr (STATS) {    // fused BN column stats (sum, sumsq)
        #pragma unroll
        for (int ni = 0; ni < 4; ++ni) {
            float s = 0.f, q = 0.f;
            #pragma unroll
            for (int mi = 0; mi < 4; ++mi)
                #pragma unroll
                for (int rg = 0; rg < 4; ++rg) {
                    const int m = m0 + wr * 64 + mi * 16 + (lane >> 4) * 4 + rg;
                    const float v = (m < M) ? acc[mi][ni][rg] : 0.f;
                    s += v; q += v * v;
                }
            s += __shfl_xor(s, 16); q += __shfl_xor(q, 16);
            s += __shfl_xor(s, 32); q += __shfl_xor(q, 32);
            if (lane < 16) {
                const int col = wc * 64 + ni * 16 + lane;
                atomicAdd(&st[col], s);
                atomicAdd(&st[256 + col], q);
            }
        }
    }
}

// W[K,256] f32 -> WT[256][ldb] bf16 transposed, zero-padded k >= K.
__global__ void wtrans_k(const float* __restrict__ W, unsigned short* __restrict__ WT,
                         int K, int ldb) {
    int total = 256 * ldb;
    for (int idx = blockIdx.x * blockDim.x + threadIdx.x; idx < total;
         idx += gridDim.x * blockDim.x) {
        int n = idx / ldb, k = idx - n * ldb;
        WT[idx] = f2bf(k < K ? W[(size_t)k * 256 + n] : 0.f);
    }
}

// per-column sum & sum-of-squares into st[0..255], st[256..511] (GAT outputs).
__global__ void colstats_k(const float* __restrict__ h, float* st, int total4) {
    const int gid    = blockIdx.x * 256 + threadIdx.x;
    const int stride = gridDim.x * 256;
    float4 s = {0.f, 0.f, 0.f, 0.f}, q = {0.f, 0.f, 0.f, 0.f};
    for (int i = gid; i < total4; i += stride) {
        float4 v = ((const float4*)h)[i];
        s.x += v.x; s.y += v.y; s.z += v.z; s.w += v.w;
        q.x += v.x * v.x; q.y += v.y * v.y; q.z += v.z * v.z; q.w += v.w * v.w;
    }
    __shared__ float red[2][4][64][4];
    const int wid = threadIdx.x >> 6, lane = threadIdx.x & 63;
    *(float4*)&red[0][wid][lane][0] = s;
    *(float4*)&red[1][wid][lane][0] = q;
    __syncthreads();
    if (wid == 0) {
        float4 s0 = *(float4*)&red[0][0][lane][0];
        float4 q0 = *(float4*)&red[1][0][lane][0];
        #pragma unroll
        for (int w = 1; w < 4; ++w) {
            float4 sw = *(float4*)&red[0][w][lane][0];
            float4 qw = *(float4*)&red[1][w][lane][0];
            s0.x += sw.x; s0.y += sw.y; s0.z += sw.z; s0.w += sw.w;
            q0.x += qw.x; q0.y += qw.y; q0.z += qw.z; q0.w += qw.w;
        }
        atomicAdd(&st[lane * 4 + 0], s0.x);
        atomicAdd(&st[lane * 4 + 1], s0.y);
        atomicAdd(&st[lane * 4 + 2], s0.z);
        atomicAdd(&st[lane * 4 + 3], s0.w);
        atomicAdd(&st[256 + lane * 4 + 0], q0.x);
        atomicAdd(&st[256 + lane * 4 + 1], q0.y);
        atomicAdd(&st[256 + lane * 4 + 2], q0.z);
        atomicAdd(&st[256 + lane * 4 + 3], q0.w);
    }
}

__global__ void bnfinal_k(const float* __restrict__ st, const float* __restrict__ g,
                          const float* __restrict__ be, float* __restrict__ ss, float invN) {
    int c = threadIdx.x;
    float mu  = st[c] * invN;
    float var = st[256 + c] * invN - mu * mu;
    float sc  = g[c] * rsqrtf(var + 1e-5f);
    ss[c]       = sc;
    ss[256 + c] = be[c] - mu * sc;
}

// y = elu(scale*v + shift); OUT_BF16 -> bf16 buffer, else f32 (may alias input)
template<bool OUT_BF16>
__global__ void bnelu_k(const float* h, const float* ss, void* outp, int total4) {
    for (int i = blockIdx.x * blockDim.x + threadIdx.x; i < total4;
         i += gridDim.x * blockDim.x) {
        float4 v = ((const float4*)h)[i];
        int c = (i << 2) & 255;
        float4 y;
        y.x = fmaf(v.x, ss[c + 0], ss[256 + c + 0]);
        y.y = fmaf(v.y, ss[c + 1], ss[256 + c + 1]);
        y.z = fmaf(v.z, ss[c + 2], ss[256 + c + 2]);
        y.w = fmaf(v.w, ss[c + 3], ss[256 + c + 3]);
        y.x = y.x > 0.f ? y.x : expm1f(y.x);
        y.y = y.y > 0.f ? y.y : expm1f(y.y);
        y.z = y.z > 0.f ? y.z : expm1f(y.z);
        y.w = y.w > 0.f ? y.w : expm1f(y.w);
        if (OUT_BF16) {
            ushort4 o;
            o.x = f2bf(y.x); o.y = f2bf(y.y); o.z = f2bf(y.z); o.w = f2bf(y.w);
            ((ushort4*)outp)[i] = o;
        } else {
            ((float4*)outp)[i] = y;
        }
    }
}

// per-row dot products with att vectors (wave per row)
__global__ void adot_k(const unsigned short* __restrict__ xl, const float* __restrict__ as_,
                       const float* __restrict__ ad_, float* __restrict__ a_src,
                       float* __restrict__ a_dst, int N) {
    int w = (blockIdx.x * blockDim.x + threadIdx.x) >> 6;
    int lane = threadIdx.x & 63;
    if (w >= N) return;
    ushort4 v = *(const ushort4*)(xl + (size_t)w * 256 + lane * 4);
    float4 s4 = *(const float4*)(as_ + lane * 4);
    float4 d4 = *(const float4*)(ad_ + lane * 4);
    float x0 = bf2f(v.x), x1 = bf2f(v.y), x2 = bf2f(v.z), x3 = bf2f(v.w);
    float ps = x0 * s4.x + x1 * s4.y + x2 * s4.z + x3 * s4.w;
    float pd = x0 * d4.x + x1 * d4.y + x2 * d4.z + x3 * d4.w;
    #pragma unroll
    for (int off = 32; off; off >>= 1) {
        ps += __shfl_xor(ps, off);
        pd += __shfl_xor(pd, off);
    }
    if (lane == 0) { a_src[w] = ps; a_dst[w] = pd; }
}

// one wave per destination node: softmax over incoming edges + weighted gather
__global__ void gat_k(const unsigned short* __restrict__ xl, const float* __restrict__ a_src,
                      const float* __restrict__ a_dst, const int* __restrict__ csr,
                      const int* __restrict__ indptr, float* __restrict__ out, int N) {
    int d = (blockIdx.x * blockDim.x + threadIdx.x) >> 6;
    int lane = threadIdx.x & 63;
    if (d >= N) return;
    int beg = indptr[d], end = indptr[d + 1];
    float adst = a_dst[d];
    float mx = -1e30f;
    for (int i = beg + lane; i < end; i += 64) {
        float e = a_src[csr[i]] + adst;
        e = e > 0.f ? e : 0.2f * e;
        mx = fmaxf(mx, e);
    }
    #pragma unroll
    for (int off = 32; off; off >>= 1) mx = fmaxf(mx, __shfl_xor(mx, off));
    float sm = 0.f;
    for (int i = beg + lane; i < end; i += 64) {
        float e = a_src[csr[i]] + adst;
        e = e > 0.f ? e : 0.2f * e;
        sm += __expf(e - mx);
    }
    #pragma unroll
    for (int off = 32; off; off >>= 1) sm += __shfl_xor(sm, off);
    float inv = 1.f / (sm + 1e-16f);
    float4 acc = {0.f, 0.f, 0.f, 0.f};
    for (int i = beg; i < end; ++i) {
        int s = csr[i];                       // uniform across wave
        float e = a_src[s] + adst;
        e = e > 0.f ? e : 0.2f * e;
        float al = __expf(e - mx) * inv;
        ushort4 v = *(const ushort4*)(xl + (size_t)s * 256 + lane * 4);
        acc.x += al * bf2f(v.x);
        acc.y += al * bf2f(v.y);
        acc.z += al * bf2f(v.z);
        acc.w += al * bf2f(v.w);
    }
    *(float4*)(out + (size_t)d * 256 + lane * 4) = acc;
}

// ---- CSR build ----
__global__ void hist_k(const int* __restrict__ edges, int* deg, int E, int N) {
    int total = E + N;
    for (int i = blockIdx.x * blockDim.x + threadIdx.x; i < total;
         i += gridDim.x * blockDim.x) {
        int dd = (i < E) ? edges[E + i] : (i - E);
        atomicAdd(&deg[dd], 1);
    }
}

__global__ void scan1_k(const int* __restrict__ deg, int* iscan, int* bsum, int N) {
    int i = blockIdx.x * 256 + threadIdx.x;
    int lane = threadIdx.x & 63, wid = threadIdx.x >> 6;
    int v = (i < N) ? deg[i] : 0;
    #pragma unroll
    for (int off = 1; off < 64; off <<= 1) {
        int u = __shfl_up(v, off);
        if (lane >= off) v += u;
    }
    __shared__ int wsum[4];
    if (lane == 63) wsum[wid] = v;
    __syncthreads();
    #pragma unroll
    for (int w = 0; w < 3; ++w) if (wid > w) v += wsum[w];
    if (i < N) iscan[i] = v;
    if (threadIdx.x == 255) bsum[blockIdx.x] = v;
}

__global__ void scan2_k(int* bsum, int nb) {   // nb <= 256
    int t = threadIdx.x;
    int lane = t & 63, wid = t >> 6;
    int v = (t < nb) ? bsum[t] : 0;
    int orig = v;
    #pragma unroll
    for (int off = 1; off < 64; off <<= 1) {
        int u = __shfl_up(v, off);
        if (lane >= off) v += u;
    }
    __shared__ int wsum[4];
    if (lane == 63) wsum[wid] = v;
    __syncthreads();
    #pragma unroll
    for (int w = 0; w < 3; ++w) if (wid > w) v += wsum[w];
    if (t < nb) bsum[t] = v - orig;            // exclusive block offsets
}

__global__ void scan3_k(const int* __restrict__ iscan, const int* __restrict__ boff,
                        int* indptr, int N) {
    int i = blockIdx.x * 256 + threadIdx.x;
    if (i < N) indptr[i + 1] = iscan[i] + boff[blockIdx.x];
    if (i == 0) indptr[0] = 0;
}

__global__ void copy_k(const int* __restrict__ a, int* b, int N) {
    for (int i = blockIdx.x * blockDim.x + threadIdx.x; i < N;
         i += gridDim.x * blockDim.x) b[i] = a[i];
}

__global__ void scatter_k(const int* __restrict__ edges, int* pos, int* csr, int E, int N) {
    int total = E + N;
    for (int i = blockIdx.x * blockDim.x + threadIdx.x; i < total;
         i += gridDim.x * blockDim.x) {
        int s  = (i < E) ? edges[i]     : (i - E);
        int dd = (i < E) ? edges[E + i] : (i - E);
        int slot = atomicAdd(&pos[dd], 1);
        csr[slot] = s;
    }
}

// ---------------------------------------------------------------------------
extern "C" void kernel_launch(void* const* d_in, const int* in_sizes, int n_in,
                              void* d_out, int out_size, void* d_ws, size_t ws_size,
                              hipStream_t stream) {
    const float* x     = (const float*)d_in[0];
    const int*   edges = (const int*)d_in[1];
    const float* W1 = (const float*)d_in[2];
    const float* W2 = (const float*)d_in[4];
    const float* W3 = (const float*)d_in[6];
    const float* g1 = (const float*)d_in[8],  *be1 = (const float*)d_in[9];
    const float* g2 = (const float*)d_in[10], *be2 = (const float*)d_in[11];
    const float* g3 = (const float*)d_in[12], *be3 = (const float*)d_in[13];
    const float* Wg1 = (const float*)d_in[14];
    const float* as1 = (const float*)d_in[15], *ad1 = (const float*)d_in[16];
    const float* g4 = (const float*)d_in[18], *be4 = (const float*)d_in[19];
    const float* Wg2 = (const float*)d_in[20];
    const float* as2 = (const float*)d_in[21], *ad2 = (const float*)d_in[22];
    const float* g5 = (const float*)d_in[24], *be5 = (const float*)d_in[25];

    const int N    = out_size / 256;
    const int K1   = in_sizes[0] / N;
    const int E    = in_sizes[1] / 2;
    const int Etot = E + N;
    const int ks1  = (K1 + 63) / 64;
    const int ldb1 = ks1 * 64;

    // workspace carve (256B aligned)
    char* p = (char*)d_ws;
    auto alloc = [&](size_t bytes) {
        char* r = p;
        p += (bytes + 255) & ~(size_t)255;
        return r;
    };
    unsigned short* W1T  = (unsigned short*)alloc((size_t)256 * ldb1 * 2);
    unsigned short* W2T  = (unsigned short*)alloc(256 * 256 * 2);
    unsigned short* W3T  = (unsigned short*)alloc(256 * 256 * 2);
    unsigned short* Wg1T = (unsigned short*)alloc(256 * 256 * 2);
    unsigned short* Wg2T = (unsigned short*)alloc(256 * 256 * 2);
    unsigned short* hn   = (unsigned short*)alloc((size_t)N * 256 * 2);
    unsigned short* xl   = (unsigned short*)alloc((size_t)N * 256 * 2);
    float* a_src  = (float*)alloc((size_t)N * 4);
    float* a_dst  = (float*)alloc((size_t)N * 4);
    int*   deg    = (int*)alloc((size_t)N * 4);
    int*   iscan  = (int*)alloc((size_t)N * 4);
    int*   bsum   = (int*)alloc(1024);
    int*   indptr = (int*)alloc((size_t)(N + 1) * 4);
    int*   pos    = (int*)alloc((size_t)N * 4);
    int*   csr    = (int*)alloc((size_t)Etot * 4);
    float* st     = (float*)alloc(512 * 4);
    float* ss     = (float*)alloc(512 * 4);
    (void)alloc(65536); // tail guard for benign over-reads
    float* out = (float*)d_out;

    const int nb = (N + 255) / 256;
    const int eg = (Etot + 255) / 256;
    const int gb = (N + 127) / 128;           // 128-row GEMM blocks
    const int t4 = N * 64;                    // (N*256)/4
    const int bg4 = (t4 + 255) / 256;

    // ---- graph CSR (shared by both GAT layers) ----
    hipMemsetAsync(deg, 0, (size_t)N * 4, stream);
    hist_k<<<eg, 256, 0, stream>>>(edges, deg, E, N);
    scan1_k<<<nb, 256, 0, stream>>>(deg, iscan, bsum, N);
    scan2_k<<<1, 256, 0, stream>>>(bsum, nb);
    scan3_k<<<nb, 256, 0, stream>>>(iscan, bsum, indptr, N);
    copy_k<<<nb, 256, 0, stream>>>(indptr, pos, N);
    scatter_k<<<eg, 256, 0, stream>>>(edges, pos, csr, E, N);

    // ---- weight prep (transpose + bf16) ----
    wtrans_k<<<(256 * ldb1 + 255) / 256, 256, 0, stream>>>(W1, W1T, K1, ldb1);
    wtrans_k<<<256, 256, 0, stream>>>(W2, W2T, 256, 256);
    wtrans_k<<<256, 256, 0, stream>>>(W3, W3T, 256, 256);
    wtrans_k<<<256, 256, 0, stream>>>(Wg1, Wg1T, 256, 256);
    wtrans_k<<<256, 256, 0, stream>>>(Wg2, Wg2T, 256, 256);

    const float invN = 1.f / (float)N;

    // ---- layer 1: x @ W1 -> BN -> ELU (bias cancels in BN; stats fused) ----
    hipMemsetAsync(st, 0, 2048, stream);
    gemm_k<true, false, true><<<gb, 512, 0, stream>>>(x, W1T, out, st, N, K1, ldb1, ks1);
    bnfinal_k<<<1, 256, 0, stream>>>(st, g1, be1, ss, invN);
    bnelu_k<true><<<bg4, 256, 0, stream>>>(out, ss, hn, t4);

    // ---- layer 2 ----
    hipMemsetAsync(st, 0, 2048, stream);
    gemm_k<false, false, true><<<gb, 512, 0, stream>>>(hn, W2T, out, st, N, 256, 256, 4);
    bnfinal_k<<<1, 256, 0, stream>>>(st, g2, be2, ss, invN);
    bnelu_k<true><<<bg4, 256, 0, stream>>>(out, ss, hn, t4);

    // ---- layer 3 ----
    hipMemsetAsync(st, 0, 2048, stream);
    gemm_k<false, false, true><<<gb, 512, 0, stream>>>(hn, W3T, out, st, N, 256, 256, 4);
    bnfinal_k<<<1, 256, 0, stream>>>(st, g3, be3, ss, invN);
    bnelu_k<true><<<bg4, 256, 0, stream>>>(out, ss, hn, t4);

    // ---- GAT layer 1 ----
    gemm_k<false, true, false><<<gb, 512, 0, stream>>>(hn, Wg1T, xl, st, N, 256, 256, 4);
    adot_k<<<(N + 3) / 4, 256, 0, stream>>>(xl, as1, ad1, a_src, a_dst, N);
    gat_k<<<(N + 3) / 4, 256, 0, stream>>>(xl, a_src, a_dst, csr, indptr, out, N);
    hipMemsetAsync(st, 0, 2048, stream);
    colstats_k<<<1024, 256, 0, stream>>>(out, st, t4);
    bnfinal_k<<<1, 256, 0, stream>>>(st, g4, be4, ss, invN);
    bnelu_k<true><<<bg4, 256, 0, stream>>>(out, ss, hn, t4);

    // ---- GAT layer 2 ----
    gemm_k<false, true, false><<<gb, 512, 0, stream>>>(hn, Wg2T, xl, st, N, 256, 256, 4);
    adot_k<<<(N + 3) / 4, 256, 0, stream>>>(xl, as2, ad2, a_src, a_dst, N);
    gat_k<<<(N + 3) / 4, 256, 0, stream>>>(xl, a_src, a_dst, csr, indptr, out, N);
    hipMemsetAsync(st, 0, 2048, stream);
    colstats_k<<<1024, 256, 0, stream>>>(out, st, t4);
    bnfinal_k<<<1, 256, 0, stream>>>(st, g5, be5, ss, invN);
    bnelu_k<false><<<bg4, 256, 0, stream>>>(out, ss, out, t4);  // final, in-place f32
}

// Round 5
// 998.306 us; speedup vs baseline: 1.4417x; 1.0277x over previous
//
#include <hip/hip_runtime.h>

#define DEV __device__ __forceinline__

typedef __attribute__((ext_vector_type(4))) float f32x4;
typedef __attribute__((ext_vector_type(8))) short short8;

DEV float bf2f(unsigned short u) {
    union { unsigned int i; float f; } c;
    c.i = ((unsigned int)u) << 16;
    return c.f;
}
DEV unsigned short f2bf(float f) {
    union { float f; unsigned int i; } c;
    c.f = f;
    unsigned int u = c.i;
    u += 0x7FFFu + ((u >> 16) & 1u);   // RTNE (finite values only here)
    return (unsigned short)(u >> 16);
}

// x f32[M][K] -> xb bf16[M][Kp], zero-padded cols K..Kp-1. Kp % 8 == 0.
// Output rows 16B-aligned; writes are 16B vector stores.
__global__ void cvt_pad_k(const float* __restrict__ x, unsigned short* __restrict__ xb,
                          int M, int K, int Kp) {
    const int gpr = Kp >> 3;                       // 8-elem groups per row
    const long long total = (long long)M * gpr;
    for (long long g = blockIdx.x * (long long)blockDim.x + threadIdx.x; g < total;
         g += (long long)gridDim.x * blockDim.x) {
        const int row = (int)(g / gpr);
        const int c8  = (int)(g - (long long)row * gpr);
        const int k0  = c8 * 8;
        const float* src = x + (size_t)row * K + k0;
        unsigned int w[4];
        if (k0 + 8 <= K) {
            f32x4 v0 = *(const f32x4*)(src);
            f32x4 v1 = *(const f32x4*)(src + 4);
            w[0] = (unsigned int)f2bf(v0[0]) | ((unsigned int)f2bf(v0[1]) << 16);
            w[1] = (unsigned int)f2bf(v0[2]) | ((unsigned int)f2bf(v0[3]) << 16);
            w[2] = (unsigned int)f2bf(v1[0]) | ((unsigned int)f2bf(v1[1]) << 16);
            w[3] = (unsigned int)f2bf(v1[2]) | ((unsigned int)f2bf(v1[3]) << 16);
        } else {
            unsigned short o[8];
            #pragma unroll
            for (int j = 0; j < 8; ++j) o[j] = (k0 + j < K) ? f2bf(src[j]) : (unsigned short)0;
            w[0] = o[0] | ((unsigned int)o[1] << 16);
            w[1] = o[2] | ((unsigned int)o[3] << 16);
            w[2] = o[4] | ((unsigned int)o[5] << 16);
            w[3] = o[6] | ((unsigned int)o[7] << 16);
        }
        *(uint4*)(xb + (size_t)row * Kp + k0) = *(uint4*)w;
    }
}

// ---------------------------------------------------------------------------
// GEMM: C[M,256] = A[M,K] @ B[K,256]; A bf16 [M][lda] (lda%8==0, rows
// 16B-aligned, OOB rows readable-garbage & masked), B pre-transposed+bf16 as
// Bt[256][ldb] zero-padded.
// BM=128, BN=256, BK=64, 512 threads = 8 waves (2 row-bands x 4 col-bands),
// each wave owns a 64x64 C tile (acc 4x4 f32x4).
// Depth-2 counted-vmcnt pipeline, all staging via global_load_lds:
// 6 vmem ops per wave per tile (2 A + 4 B) -> s_waitcnt vmcnt(6) waits for
// the PREVIOUS tile while the just-issued tile stays in flight.
// LDS [row][chunk] with chunk XOR-swizzle (c ^= row&7), chunk = 8 bf16.
// ---------------------------------------------------------------------------
template<bool OUT_BF16, bool STATS>
__launch_bounds__(512)
__global__ void gemm_k(const unsigned short* __restrict__ A,
                       const unsigned short* __restrict__ Bt,
                       void* __restrict__ Cptr,
                       float* __restrict__ st,
                       int M, int lda, int ldb, int ksteps)
{
    __shared__ __align__(16) unsigned short As[2][128 * 64];
    __shared__ __align__(16) unsigned short Bs[2][256 * 64];
    const int t    = threadIdx.x;
    const int wid  = t >> 6;       // 0..7
    const int lane = t & 63;
    const int wr   = wid >> 2;     // 0..1  (64-row band)
    const int wc   = wid & 3;      // 0..3  (64-col band)
    const int m0   = blockIdx.x * 128;

    f32x4 acc[4][4] = {};

    auto stageB = [&](int buf, int ks) {       // 4 global_load_lds per wave
        const int k0 = ks * 64;
        #pragma unroll
        for (int is = 0; is < 4; ++is) {
            const int rbase = wid * 32 + is * 8;
            const int rr  = rbase + (lane >> 3);
            const int csw = (lane & 7) ^ (rr & 7);         // pre-swizzled source
            __builtin_amdgcn_global_load_lds(
                (const __attribute__((address_space(1))) void*)(Bt + (size_t)rr * ldb + k0 + csw * 8),
                (__attribute__((address_space(3))) void*)(&Bs[buf][rbase * 64]),
                16, 0, 0);
        }
    };
    auto stageA = [&](int buf, int ks) {       // 2 global_load_lds per wave
        const int k0 = ks * 64;
        #pragma unroll
        for (int is = 0; is < 2; ++is) {
            const int rbase = wid * 16 + is * 8;
            const int rr  = rbase + (lane >> 3);
            const int csw = (lane & 7) ^ (rr & 7);
            __builtin_amdgcn_global_load_lds(
                (const __attribute__((address_space(1))) void*)(A + (size_t)(m0 + rr) * lda + k0 + csw * 8),
                (__attribute__((address_space(3))) void*)(&As[buf][rbase * 64]),
                16, 0, 0);
        }
    };
    auto compute = [&](int buf) {
        #pragma unroll
        for (int kk = 0; kk < 2; ++kk) {
            short8 af[4], bfr[4];
            #pragma unroll
            for (int mi = 0; mi < 4; ++mi) {
                const int r   = wr * 64 + mi * 16 + (lane & 15);
                const int csw = (kk * 4 + (lane >> 4)) ^ (r & 7);
                af[mi] = *(const short8*)(&As[buf][r * 64 + csw * 8]);
            }
            #pragma unroll
            for (int ni = 0; ni < 4; ++ni) {
                const int r   = wc * 64 + ni * 16 + (lane & 15);
                const int csw = (kk * 4 + (lane >> 4)) ^ (r & 7);
                bfr[ni] = *(const short8*)(&Bs[buf][r * 64 + csw * 8]);
            }
            #pragma unroll
            for (int mi = 0; mi < 4; ++mi)
                #pragma unroll
                for (int ni = 0; ni < 4; ++ni)
                    acc[mi][ni] = __builtin_amdgcn_mfma_f32_16x16x32_bf16(
                        af[mi], bfr[ni], acc[mi][ni], 0, 0, 0);
        }
    };

    // ---- prologue: tiles 0 and 1 in flight ----
    stageA(0, 0); stageB(0, 0);
    __builtin_amdgcn_sched_barrier(0);
    stageA(1, 1); stageB(1, 1);
    asm volatile("s_waitcnt vmcnt(6)" ::: "memory");   // tile 0 landed
    __builtin_amdgcn_sched_barrier(0);
    __builtin_amdgcn_s_barrier();
    __builtin_amdgcn_sched_barrier(0);

    // ---- main loop ----
    int cur = 0;
    for (int k = 0; k < ksteps; ++k) {
        compute(cur);                            // tile k from buf[cur]
        if (k + 1 >= ksteps) break;
        __builtin_amdgcn_sched_barrier(0);
        __builtin_amdgcn_s_barrier();            // buf[cur] free for overwrite
        __builtin_amdgcn_sched_barrier(0);
        if (k + 2 < ksteps) {
            stageA(cur, k + 2);
            stageB(cur, k + 2);
            asm volatile("s_waitcnt vmcnt(6)" ::: "memory");  // tile k+1 landed
        } else {
            asm volatile("s_waitcnt vmcnt(0)" ::: "memory");
        }
        __builtin_amdgcn_sched_barrier(0);
        __builtin_amdgcn_s_barrier();            // buf[cur^1] ready
        __builtin_amdgcn_sched_barrier(0);
        cur ^= 1;
    }

    // ---- epilogue: C col = lane&15, row = (lane>>4)*4 + reg ----
    #pragma unroll
    for (int mi = 0; mi < 4; ++mi) {
        #pragma unroll
        for (int ni = 0; ni < 4; ++ni) {
            const int col = wc * 64 + ni * 16 + (lane & 15);
            #pragma unroll
            for (int rg = 0; rg < 4; ++rg) {
                const int m = m0 + wr * 64 + mi * 16 + (lane >> 4) * 4 + rg;
                if (m < M) {
                    if constexpr (OUT_BF16)
                        ((unsigned short*)Cptr)[(size_t)m * 256 + col] = f2bf(acc[mi][ni][rg]);
                    else
                        ((float*)Cptr)[(size_t)m * 256 + col] = acc[mi][ni][rg];
                }
            }
        }
    }
    if constexpr (STATS) {    // fused BN column stats (sum, sumsq)
        #pragma unroll
        for (int ni = 0; ni < 4; ++ni) {
            float s = 0.f, q = 0.f;
            #pragma unroll
            for (int mi = 0; mi < 4; ++mi)
                #pragma unroll
                for (int rg = 0; rg < 4; ++rg) {
                    const int m = m0 + wr * 64 + mi * 16 + (lane >> 4) * 4 + rg;
                    const float v = (m < M) ? acc[mi][ni][rg] : 0.f;
                    s += v; q += v * v;
                }
            s += __shfl_xor(s, 16); q += __shfl_xor(q, 16);
            s += __shfl_xor(s, 32); q += __shfl_xor(q, 32);
            if (lane < 16) {
                const int col = wc * 64 + ni * 16 + lane;
                atomicAdd(&st[col], s);
                atomicAdd(&st[256 + col], q);
            }
        }
    }
}

// W[K,256] f32 -> WT[256][ldb] bf16 transposed, zero-padded k >= K.
__global__ void wtrans_k(const float* __restrict__ W, unsigned short* __restrict__ WT,
                         int K, int ldb) {
    int total = 256 * ldb;
    for (int idx = blockIdx.x * blockDim.x + threadIdx.x; idx < total;
         idx += gridDim.x * blockDim.x) {
        int n = idx / ldb, k = idx - n * ldb;
        WT[idx] = f2bf(k < K ? W[(size_t)k * 256 + n] : 0.f);
    }
}

// per-column sum & sum-of-squares into st[0..255], st[256..511] (GAT outputs).
__global__ void colstats_k(const float* __restrict__ h, float* st, int total4) {
    const int gid    = blockIdx.x * 256 + threadIdx.x;
    const int stride = gridDim.x * 256;
    float4 s = {0.f, 0.f, 0.f, 0.f}, q = {0.f, 0.f, 0.f, 0.f};
    for (int i = gid; i < total4; i += stride) {
        float4 v = ((const float4*)h)[i];
        s.x += v.x; s.y += v.y; s.z += v.z; s.w += v.w;
        q.x += v.x * v.x; q.y += v.y * v.y; q.z += v.z * v.z; q.w += v.w * v.w;
    }
    __shared__ float red[2][4][64][4];
    const int wid = threadIdx.x >> 6, lane = threadIdx.x & 63;
    *(float4*)&red[0][wid][lane][0] = s;
    *(float4*)&red[1][wid][lane][0] = q;
    __syncthreads();
    if (wid == 0) {
        float4 s0 = *(float4*)&red[0][0][lane][0];
        float4 q0 = *(float4*)&red[1][0][lane][0];
        #pragma unroll
        for (int w = 1; w < 4; ++w) {
            float4 sw = *(float4*)&red[0][w][lane][0];
            float4 qw = *(float4*)&red[1][w][lane][0];
            s0.x += sw.x; s0.y += sw.y; s0.z += sw.z; s0.w += sw.w;
            q0.x += qw.x; q0.y += qw.y; q0.z += qw.z; q0.w += qw.w;
        }
        atomicAdd(&st[lane * 4 + 0], s0.x);
        atomicAdd(&st[lane * 4 + 1], s0.y);
        atomicAdd(&st[lane * 4 + 2], s0.z);
        atomicAdd(&st[lane * 4 + 3], s0.w);
        atomicAdd(&st[256 + lane * 4 + 0], q0.x);
        atomicAdd(&st[256 + lane * 4 + 1], q0.y);
        atomicAdd(&st[256 + lane * 4 + 2], q0.z);
        atomicAdd(&st[256 + lane * 4 + 3], q0.w);
    }
}

__global__ void bnfinal_k(const float* __restrict__ st, const float* __restrict__ g,
                          const float* __restrict__ be, float* __restrict__ ss, float invN) {
    int c = threadIdx.x;
    float mu  = st[c] * invN;
    float var = st[256 + c] * invN - mu * mu;
    float sc  = g[c] * rsqrtf(var + 1e-5f);
    ss[c]       = sc;
    ss[256 + c] = be[c] - mu * sc;
}

// y = elu(scale*v + shift); OUT_BF16 -> bf16 buffer, else f32 (may alias input)
template<bool OUT_BF16>
__global__ void bnelu_k(const float* h, const float* ss, void* outp, int total4) {
    for (int i = blockIdx.x * blockDim.x + threadIdx.x; i < total4;
         i += gridDim.x * blockDim.x) {
        float4 v = ((const float4*)h)[i];
        int c = (i << 2) & 255;
        float4 y;
        y.x = fmaf(v.x, ss[c + 0], ss[256 + c + 0]);
        y.y = fmaf(v.y, ss[c + 1], ss[256 + c + 1]);
        y.z = fmaf(v.z, ss[c + 2], ss[256 + c + 2]);
        y.w = fmaf(v.w, ss[c + 3], ss[256 + c + 3]);
        y.x = y.x > 0.f ? y.x : expm1f(y.x);
        y.y = y.y > 0.f ? y.y : expm1f(y.y);
        y.z = y.z > 0.f ? y.z : expm1f(y.z);
        y.w = y.w > 0.f ? y.w : expm1f(y.w);
        if (OUT_BF16) {
            ushort4 o;
            o.x = f2bf(y.x); o.y = f2bf(y.y); o.z = f2bf(y.z); o.w = f2bf(y.w);
            ((ushort4*)outp)[i] = o;
        } else {
            ((float4*)outp)[i] = y;
        }
    }
}

// per-row dot products with att vectors (wave per row)
__global__ void adot_k(const unsigned short* __restrict__ xl, const float* __restrict__ as_,
                       const float* __restrict__ ad_, float* __restrict__ a_src,
                       float* __restrict__ a_dst, int N) {
    int w = (blockIdx.x * blockDim.x + threadIdx.x) >> 6;
    int lane = threadIdx.x & 63;
    if (w >= N) return;
    ushort4 v = *(const ushort4*)(xl + (size_t)w * 256 + lane * 4);
    float4 s4 = *(const float4*)(as_ + lane * 4);
    float4 d4 = *(const float4*)(ad_ + lane * 4);
    float x0 = bf2f(v.x), x1 = bf2f(v.y), x2 = bf2f(v.z), x3 = bf2f(v.w);
    float ps = x0 * s4.x + x1 * s4.y + x2 * s4.z + x3 * s4.w;
    float pd = x0 * d4.x + x1 * d4.y + x2 * d4.z + x3 * d4.w;
    #pragma unroll
    for (int off = 32; off; off >>= 1) {
        ps += __shfl_xor(ps, off);
        pd += __shfl_xor(pd, off);
    }
    if (lane == 0) { a_src[w] = ps; a_dst[w] = pd; }
}

DEV float lrelu(float e) { return e > 0.f ? e : 0.2f * e; }

// one wave per destination node: softmax over incoming edges + weighted gather.
// Gather loop unrolled x4 with independent accumulators for memory-level par.
__global__ void gat_k(const unsigned short* __restrict__ xl, const float* __restrict__ a_src,
                      const float* __restrict__ a_dst, const int* __restrict__ csr,
                      const int* __restrict__ indptr, float* __restrict__ out, int N) {
    int d = (blockIdx.x * blockDim.x + threadIdx.x) >> 6;
    int lane = threadIdx.x & 63;
    if (d >= N) return;
    int beg = indptr[d], end = indptr[d + 1];
    float adst = a_dst[d];
    float mx = -1e30f;
    for (int i = beg + lane; i < end; i += 64)
        mx = fmaxf(mx, lrelu(a_src[csr[i]] + adst));
    #pragma unroll
    for (int off = 32; off; off >>= 1) mx = fmaxf(mx, __shfl_xor(mx, off));
    float sm = 0.f;
    for (int i = beg + lane; i < end; i += 64)
        sm += __expf(lrelu(a_src[csr[i]] + adst) - mx);
    #pragma unroll
    for (int off = 32; off; off >>= 1) sm += __shfl_xor(sm, off);
    float inv = 1.f / (sm + 1e-16f);

    float4 A0 = {0,0,0,0}, A1 = {0,0,0,0}, A2 = {0,0,0,0}, A3 = {0,0,0,0};
    int i = beg;
    for (; i + 4 <= end; i += 4) {
        int s0 = csr[i], s1 = csr[i+1], s2 = csr[i+2], s3 = csr[i+3];
        float w0 = __expf(lrelu(a_src[s0] + adst) - mx) * inv;
        float w1 = __expf(lrelu(a_src[s1] + adst) - mx) * inv;
        float w2 = __expf(lrelu(a_src[s2] + adst) - mx) * inv;
        float w3 = __expf(lrelu(a_src[s3] + adst) - mx) * inv;
        ushort4 v0 = *(const ushort4*)(xl + (size_t)s0 * 256 + lane * 4);
        ushort4 v1 = *(const ushort4*)(xl + (size_t)s1 * 256 + lane * 4);
        ushort4 v2 = *(const ushort4*)(xl + (size_t)s2 * 256 + lane * 4);
        ushort4 v3 = *(const ushort4*)(xl + (size_t)s3 * 256 + lane * 4);
        A0.x += w0 * bf2f(v0.x); A0.y += w0 * bf2f(v0.y); A0.z += w0 * bf2f(v0.z); A0.w += w0 * bf2f(v0.w);
        A1.x += w1 * bf2f(v1.x); A1.y += w1 * bf2f(v1.y); A1.z += w1 * bf2f(v1.z); A1.w += w1 * bf2f(v1.w);
        A2.x += w2 * bf2f(v2.x); A2.y += w2 * bf2f(v2.y); A2.z += w2 * bf2f(v2.z); A2.w += w2 * bf2f(v2.w);
        A3.x += w3 * bf2f(v3.x); A3.y += w3 * bf2f(v3.y); A3.z += w3 * bf2f(v3.z); A3.w += w3 * bf2f(v3.w);
    }
    for (; i < end; ++i) {
        int s = csr[i];
        float w = __expf(lrelu(a_src[s] + adst) - mx) * inv;
        ushort4 v = *(const ushort4*)(xl + (size_t)s * 256 + lane * 4);
        A0.x += w * bf2f(v.x); A0.y += w * bf2f(v.y);
        A0.z += w * bf2f(v.z); A0.w += w * bf2f(v.w);
    }
    A0.x += A1.x + A2.x + A3.x;
    A0.y += A1.y + A2.y + A3.y;
    A0.z += A1.z + A2.z + A3.z;
    A0.w += A1.w + A2.w + A3.w;
    *(float4*)(out + (size_t)d * 256 + lane * 4) = A0;
}

// ---- CSR build ----
__global__ void hist_k(const int* __restrict__ edges, int* deg, int E, int N) {
    int total = E + N;
    for (int i = blockIdx.x * blockDim.x + threadIdx.x; i < total;
         i += gridDim.x * blockDim.x) {
        int dd = (i < E) ? edges[E + i] : (i - E);
        atomicAdd(&deg[dd], 1);
    }
}

__global__ void scan1_k(const int* __restrict__ deg, int* iscan, int* bsum, int N) {
    int i = blockIdx.x * 256 + threadIdx.x;
    int lane = threadIdx.x & 63, wid = threadIdx.x >> 6;
    int v = (i < N) ? deg[i] : 0;
    #pragma unroll
    for (int off = 1; off < 64; off <<= 1) {
        int u = __shfl_up(v, off);
        if (lane >= off) v += u;
    }
    __shared__ int wsum[4];
    if (lane == 63) wsum[wid] = v;
    __syncthreads();
    #pragma unroll
    for (int w = 0; w < 3; ++w) if (wid > w) v += wsum[w];
    if (i < N) iscan[i] = v;
    if (threadIdx.x == 255) bsum[blockIdx.x] = v;
}

__global__ void scan2_k(int* bsum, int nb) {   // nb <= 256
    int t = threadIdx.x;
    int lane = t & 63, wid = t >> 6;
    int v = (t < nb) ? bsum[t] : 0;
    int orig = v;
    #pragma unroll
    for (int off = 1; off < 64; off <<= 1) {
        int u = __shfl_up(v, off);
        if (lane >= off) v += u;
    }
    __shared__ int wsum[4];
    if (lane == 63) wsum[wid] = v;
    __syncthreads();
    #pragma unroll
    for (int w = 0; w < 3; ++w) if (wid > w) v += wsum[w];
    if (t < nb) bsum[t] = v - orig;            // exclusive block offsets
}

__global__ void scan3_k(const int* __restrict__ iscan, const int* __restrict__ boff,
                        int* indptr, int N) {
    int i = blockIdx.x * 256 + threadIdx.x;
    if (i < N) indptr[i + 1] = iscan[i] + boff[blockIdx.x];
    if (i == 0) indptr[0] = 0;
}

__global__ void copy_k(const int* __restrict__ a, int* b, int N) {
    for (int i = blockIdx.x * blockDim.x + threadIdx.x; i < N;
         i += gridDim.x * blockDim.x) b[i] = a[i];
}

__global__ void scatter_k(const int* __restrict__ edges, int* pos, int* csr, int E, int N) {
    int total = E + N;
    for (int i = blockIdx.x * blockDim.x + threadIdx.x; i < total;
         i += gridDim.x * blockDim.x) {
        int s  = (i < E) ? edges[i]     : (i - E);
        int dd = (i < E) ? edges[E + i] : (i - E);
        int slot = atomicAdd(&pos[dd], 1);
        csr[slot] = s;
    }
}

// ---------------------------------------------------------------------------
extern "C" void kernel_launch(void* const* d_in, const int* in_sizes, int n_in,
                              void* d_out, int out_size, void* d_ws, size_t ws_size,
                              hipStream_t stream) {
    const float* x     = (const float*)d_in[0];
    const int*   edges = (const int*)d_in[1];
    const float* W1 = (const float*)d_in[2];
    const float* W2 = (const float*)d_in[4];
    const float* W3 = (const float*)d_in[6];
    const float* g1 = (const float*)d_in[8],  *be1 = (const float*)d_in[9];
    const float* g2 = (const float*)d_in[10], *be2 = (const float*)d_in[11];
    const float* g3 = (const float*)d_in[12], *be3 = (const float*)d_in[13];
    const float* Wg1 = (const float*)d_in[14];
    const float* as1 = (const float*)d_in[15], *ad1 = (const float*)d_in[16];
    const float* g4 = (const float*)d_in[18], *be4 = (const float*)d_in[19];
    const float* Wg2 = (const float*)d_in[20];
    const float* as2 = (const float*)d_in[21], *ad2 = (const float*)d_in[22];
    const float* g5 = (const float*)d_in[24], *be5 = (const float*)d_in[25];

    const int N    = out_size / 256;
    const int K1   = in_sizes[0] / N;
    const int E    = in_sizes[1] / 2;
    const int Etot = E + N;
    const int ks1  = (K1 + 63) / 64;
    const int ldb1 = ks1 * 64;                // padded K (2624)

    // workspace carve (256B aligned)
    char* p = (char*)d_ws;
    auto alloc = [&](size_t bytes) {
        char* r = p;
        p += (bytes + 255) & ~(size_t)255;
        return r;
    };
    unsigned short* W1T  = (unsigned short*)alloc((size_t)256 * ldb1 * 2);
    unsigned short* W2T  = (unsigned short*)alloc(256 * 256 * 2);
    unsigned short* W3T  = (unsigned short*)alloc(256 * 256 * 2);
    unsigned short* Wg1T = (unsigned short*)alloc(256 * 256 * 2);
    unsigned short* Wg2T = (unsigned short*)alloc(256 * 256 * 2);
    unsigned short* xb   = (unsigned short*)alloc((size_t)N * ldb1 * 2);  // bf16 x, padded
    unsigned short* hn   = (unsigned short*)alloc((size_t)N * 256 * 2);
    unsigned short* xl   = (unsigned short*)alloc((size_t)N * 256 * 2);
    float* a_src  = (float*)alloc((size_t)N * 4);
    float* a_dst  = (float*)alloc((size_t)N * 4);
    int*   deg    = (int*)alloc((size_t)N * 4);
    int*   iscan  = (int*)alloc((size_t)N * 4);
    int*   bsum   = (int*)alloc(1024);
    int*   indptr = (int*)alloc((size_t)(N + 1) * 4);
    int*   pos    = (int*)alloc((size_t)N * 4);
    int*   csr    = (int*)alloc((size_t)Etot * 4);
    float* st     = (float*)alloc(512 * 4);
    float* ss     = (float*)alloc(512 * 4);
    (void)alloc(1 << 19); // 512KB tail guard (benign OOB reads of last tile rows)
    float* out = (float*)d_out;

    const int nb = (N + 255) / 256;
    const int eg = (Etot + 255) / 256;
    const int gb = (N + 127) / 128;           // 128-row GEMM blocks
    const int t4 = N * 64;                    // (N*256)/4
    const int bg4 = (t4 + 255) / 256;

    // ---- graph CSR (shared by both GAT layers) ----
    hipMemsetAsync(deg, 0, (size_t)N * 4, stream);
    hist_k<<<eg, 256, 0, stream>>>(edges, deg, E, N);
    scan1_k<<<nb, 256, 0, stream>>>(deg, iscan, bsum, N);
    scan2_k<<<1, 256, 0, stream>>>(bsum, nb);
    scan3_k<<<nb, 256, 0, stream>>>(iscan, bsum, indptr, N);
    copy_k<<<nb, 256, 0, stream>>>(indptr, pos, N);
    scatter_k<<<eg, 256, 0, stream>>>(edges, pos, csr, E, N);

    // ---- weight prep (transpose + bf16) + x conversion ----
    wtrans_k<<<(256 * ldb1 + 255) / 256, 256, 0, stream>>>(W1, W1T, K1, ldb1);
    wtrans_k<<<256, 256, 0, stream>>>(W2, W2T, 256, 256);
    wtrans_k<<<256, 256, 0, stream>>>(W3, W3T, 256, 256);
    wtrans_k<<<256, 256, 0, stream>>>(Wg1, Wg1T, 256, 256);
    wtrans_k<<<256, 256, 0, stream>>>(Wg2, Wg2T, 256, 256);
    cvt_pad_k<<<2048, 256, 0, stream>>>(x, xb, N, K1, ldb1);

    const float invN = 1.f / (float)N;

    // ---- layer 1: x @ W1 -> BN -> ELU (bias cancels in BN; stats fused) ----
    hipMemsetAsync(st, 0, 2048, stream);
    gemm_k<false, true><<<gb, 512, 0, stream>>>(xb, W1T, out, st, N, ldb1, ldb1, ks1);
    bnfinal_k<<<1, 256, 0, stream>>>(st, g1, be1, ss, invN);
    bnelu_k<true><<<bg4, 256, 0, stream>>>(out, ss, hn, t4);

    // ---- layer 2 ----
    hipMemsetAsync(st, 0, 2048, stream);
    gemm_k<false, true><<<gb, 512, 0, stream>>>(hn, W2T, out, st, N, 256, 256, 4);
    bnfinal_k<<<1, 256, 0, stream>>>(st, g2, be2, ss, invN);
    bnelu_k<true><<<bg4, 256, 0, stream>>>(out, ss, hn, t4);

    // ---- layer 3 ----
    hipMemsetAsync(st, 0, 2048, stream);
    gemm_k<false, true><<<gb, 512, 0, stream>>>(hn, W3T, out, st, N, 256, 256, 4);
    bnfinal_k<<<1, 256, 0, stream>>>(st, g3, be3, ss, invN);
    bnelu_k<true><<<bg4, 256, 0, stream>>>(out, ss, hn, t4);

    // ---- GAT layer 1 ----
    gemm_k<true, false><<<gb, 512, 0, stream>>>(hn, Wg1T, xl, st, N, 256, 256, 4);
    adot_k<<<(N + 3) / 4, 256, 0, stream>>>(xl, as1, ad1, a_src, a_dst, N);
    gat_k<<<(N + 3) / 4, 256, 0, stream>>>(xl, a_src, a_dst, csr, indptr, out, N);
    hipMemsetAsync(st, 0, 2048, stream);
    colstats_k<<<1024, 256, 0, stream>>>(out, st, t4);
    bnfinal_k<<<1, 256, 0, stream>>>(st, g4, be4, ss, invN);
    bnelu_k<true><<<bg4, 256, 0, stream>>>(out, ss, hn, t4);

    // ---- GAT layer 2 ----
    gemm_k<true, false><<<gb, 512, 0, stream>>>(hn, Wg2T, xl, st, N, 256, 256, 4);
    adot_k<<<(N + 3) / 4, 256, 0, stream>>>(xl, as2, ad2, a_src, a_dst, N);
    gat_k<<<(N + 3) / 4, 256, 0, stream>>>(xl, a_src, a_dst, csr, indptr, out, N);
    hipMemsetAsync(st, 0, 2048, stream);
    colstats_k<<<1024, 256, 0, stream>>>(out, st, t4);
    bnfinal_k<<<1, 256, 0, stream>>>(st, g5, be5, ss, invN);
    bnelu_k<false><<<bg4, 256, 0, stream>>>(out, ss, out, t4);  // final, in-place f32
}

// Round 6
// 966.431 us; speedup vs baseline: 1.4893x; 1.0330x over previous
//
#include <hip/hip_runtime.h>

#define DEV __device__ __forceinline__

typedef __attribute__((ext_vector_type(4))) float f32x4;
typedef __attribute__((ext_vector_type(8))) short short8;

DEV float bf2f(unsigned short u) {
    union { unsigned int i; float f; } c;
    c.i = ((unsigned int)u) << 16;
    return c.f;
}
DEV unsigned short f2bf(float f) {
    union { float f; unsigned int i; } c;
    c.f = f;
    unsigned int u = c.i;
    u += 0x7FFFu + ((u >> 16) & 1u);   // RTNE (finite values only here)
    return (unsigned short)(u >> 16);
}

// x f32[M][K] -> xb bf16[M][Kp], zero-padded cols K..Kp-1. Kp % 8 == 0.
__global__ void cvt_pad_k(const float* __restrict__ x, unsigned short* __restrict__ xb,
                          int M, int K, int Kp) {
    const int gpr = Kp >> 3;                       // 8-elem groups per row
    const long long total = (long long)M * gpr;
    for (long long g = blockIdx.x * (long long)blockDim.x + threadIdx.x; g < total;
         g += (long long)gridDim.x * blockDim.x) {
        const int row = (int)(g / gpr);
        const int c8  = (int)(g - (long long)row * gpr);
        const int k0  = c8 * 8;
        const float* src = x + (size_t)row * K + k0;
        unsigned int w[4];
        if (k0 + 8 <= K) {
            f32x4 v0 = *(const f32x4*)(src);
            f32x4 v1 = *(const f32x4*)(src + 4);
            w[0] = (unsigned int)f2bf(v0[0]) | ((unsigned int)f2bf(v0[1]) << 16);
            w[1] = (unsigned int)f2bf(v0[2]) | ((unsigned int)f2bf(v0[3]) << 16);
            w[2] = (unsigned int)f2bf(v1[0]) | ((unsigned int)f2bf(v1[1]) << 16);
            w[3] = (unsigned int)f2bf(v1[2]) | ((unsigned int)f2bf(v1[3]) << 16);
        } else {
            unsigned short o[8];
            #pragma unroll
            for (int j = 0; j < 8; ++j) o[j] = (k0 + j < K) ? f2bf(src[j]) : (unsigned short)0;
            w[0] = o[0] | ((unsigned int)o[1] << 16);
            w[1] = o[2] | ((unsigned int)o[3] << 16);
            w[2] = o[4] | ((unsigned int)o[5] << 16);
            w[3] = o[6] | ((unsigned int)o[7] << 16);
        }
        *(uint4*)(xb + (size_t)row * Kp + k0) = *(uint4*)w;
    }
}

// ---------------------------------------------------------------------------
// GEMM: C[M,256] = A[M,K] @ B[K,256]; A bf16 [M][lda] (lda%8==0, benign OOB
// row reads masked at epilogue), B pre-transposed+bf16 Bt[256][ldb], 0-padded.
// BM=128, BN=256, BK=64, 512 threads = 8 waves (2x4), 64x64 C tile per wave.
// DEPTH-3 counted-vmcnt pipeline (3 LDS buffers, 144KB): tile k+3 is issued
// right after buf free; s_waitcnt vmcnt(12) = 2 tiles in flight, so each
// tile's loads get ~2 compute phases (~800cy) to cover ~900cy HBM latency.
// Per-wave vmem ops per tile: 6 (2 A + 4 B global_load_lds). ksteps >= 3.
// C written bf16; optional fused per-column BN stats (f32-exact from acc).
// LDS [row][chunk] with chunk XOR-swizzle (c ^= row&7), chunk = 8 bf16.
// ---------------------------------------------------------------------------
template<bool STATS>
__launch_bounds__(512)
__global__ void gemm_k(const unsigned short* __restrict__ A,
                       const unsigned short* __restrict__ Bt,
                       unsigned short* __restrict__ C,
                       float* __restrict__ st,
                       int M, int lda, int ldb, int ksteps)
{
    __shared__ __align__(16) unsigned short As[3][128 * 64];
    __shared__ __align__(16) unsigned short Bs[3][256 * 64];
    const int t    = threadIdx.x;
    const int wid  = t >> 6;       // 0..7
    const int lane = t & 63;
    const int wr   = wid >> 2;     // 0..1  (64-row band)
    const int wc   = wid & 3;      // 0..3  (64-col band)
    const int m0   = blockIdx.x * 128;

    f32x4 acc[4][4] = {};

    auto stage = [&](int buf, int ks) {        // 6 global_load_lds per wave
        const int k0 = ks * 64;
        #pragma unroll
        for (int is = 0; is < 2; ++is) {       // A: 128x64 tile
            const int rbase = wid * 16 + is * 8;
            const int rr  = rbase + (lane >> 3);
            const int csw = (lane & 7) ^ (rr & 7);
            __builtin_amdgcn_global_load_lds(
                (const __attribute__((address_space(1))) void*)(A + (size_t)(m0 + rr) * lda + k0 + csw * 8),
                (__attribute__((address_space(3))) void*)(&As[buf][rbase * 64]),
                16, 0, 0);
        }
        #pragma unroll
        for (int is = 0; is < 4; ++is) {       // B: 256x64 tile
            const int rbase = wid * 32 + is * 8;
            const int rr  = rbase + (lane >> 3);
            const int csw = (lane & 7) ^ (rr & 7);
            __builtin_amdgcn_global_load_lds(
                (const __attribute__((address_space(1))) void*)(Bt + (size_t)rr * ldb + k0 + csw * 8),
                (__attribute__((address_space(3))) void*)(&Bs[buf][rbase * 64]),
                16, 0, 0);
        }
    };
    auto compute = [&](int buf) {
        #pragma unroll
        for (int kk = 0; kk < 2; ++kk) {
            short8 af[4], bfr[4];
            #pragma unroll
            for (int mi = 0; mi < 4; ++mi) {
                const int r   = wr * 64 + mi * 16 + (lane & 15);
                const int csw = (kk * 4 + (lane >> 4)) ^ (r & 7);
                af[mi] = *(const short8*)(&As[buf][r * 64 + csw * 8]);
            }
            #pragma unroll
            for (int ni = 0; ni < 4; ++ni) {
                const int r   = wc * 64 + ni * 16 + (lane & 15);
                const int csw = (kk * 4 + (lane >> 4)) ^ (r & 7);
                bfr[ni] = *(const short8*)(&Bs[buf][r * 64 + csw * 8]);
            }
            #pragma unroll
            for (int mi = 0; mi < 4; ++mi)
                #pragma unroll
                for (int ni = 0; ni < 4; ++ni)
                    acc[mi][ni] = __builtin_amdgcn_mfma_f32_16x16x32_bf16(
                        af[mi], bfr[ni], acc[mi][ni], 0, 0, 0);
        }
    };

    // ---- prologue: tiles 0,1,2 in flight (ksteps >= 3) ----
    stage(0, 0);
    __builtin_amdgcn_sched_barrier(0);
    stage(1, 1);
    __builtin_amdgcn_sched_barrier(0);
    stage(2, 2);
    asm volatile("s_waitcnt vmcnt(12)" ::: "memory");   // tile 0 landed
    __builtin_amdgcn_sched_barrier(0);
    __builtin_amdgcn_s_barrier();
    __builtin_amdgcn_sched_barrier(0);

    // ---- main loop ----
    int cur = 0;
    for (int k = 0; k < ksteps; ++k) {
        compute(cur);                            // tile k from buf[cur]
        if (k + 1 >= ksteps) break;
        __builtin_amdgcn_sched_barrier(0);
        __builtin_amdgcn_s_barrier();            // buf[cur] free for overwrite
        __builtin_amdgcn_sched_barrier(0);
        if (k + 3 < ksteps) {
            stage(cur, k + 3);
            asm volatile("s_waitcnt vmcnt(12)" ::: "memory");  // tile k+1 landed
        } else if (k + 2 < ksteps) {
            asm volatile("s_waitcnt vmcnt(6)" ::: "memory");   // tile k+1 landed
        } else {
            asm volatile("s_waitcnt vmcnt(0)" ::: "memory");
        }
        __builtin_amdgcn_sched_barrier(0);
        __builtin_amdgcn_s_barrier();            // next buf ready
        __builtin_amdgcn_sched_barrier(0);
        cur = (cur == 2) ? 0 : cur + 1;
    }

    // ---- epilogue: bf16 C; col = lane&15 of band, row = (lane>>4)*4 + rg ----
    #pragma unroll
    for (int mi = 0; mi < 4; ++mi) {
        #pragma unroll
        for (int ni = 0; ni < 4; ++ni) {
            const int col = wc * 64 + ni * 16 + (lane & 15);
            #pragma unroll
            for (int rg = 0; rg < 4; ++rg) {
                const int m = m0 + wr * 64 + mi * 16 + (lane >> 4) * 4 + rg;
                if (m < M)
                    C[(size_t)m * 256 + col] = f2bf(acc[mi][ni][rg]);
            }
        }
    }
    if constexpr (STATS) {    // fused BN column stats (sum, sumsq), f32-exact
        #pragma unroll
        for (int ni = 0; ni < 4; ++ni) {
            float s = 0.f, q = 0.f;
            #pragma unroll
            for (int mi = 0; mi < 4; ++mi)
                #pragma unroll
                for (int rg = 0; rg < 4; ++rg) {
                    const int m = m0 + wr * 64 + mi * 16 + (lane >> 4) * 4 + rg;
                    const float v = (m < M) ? acc[mi][ni][rg] : 0.f;
                    s += v; q += v * v;
                }
            s += __shfl_xor(s, 16); q += __shfl_xor(q, 16);
            s += __shfl_xor(s, 32); q += __shfl_xor(q, 32);
            if (lane < 16) {
                const int col = wc * 64 + ni * 16 + lane;
                atomicAdd(&st[col], s);
                atomicAdd(&st[256 + col], q);
            }
        }
    }
}

// W[K,256] f32 -> WT[256][ldb] bf16 transposed, zero-padded k >= K.
__global__ void wtrans_k(const float* __restrict__ W, unsigned short* __restrict__ WT,
                         int K, int ldb) {
    int total = 256 * ldb;
    for (int idx = blockIdx.x * blockDim.x + threadIdx.x; idx < total;
         idx += gridDim.x * blockDim.x) {
        int n = idx / ldb, k = idx - n * ldb;
        WT[idx] = f2bf(k < K ? W[(size_t)k * 256 + n] : 0.f);
    }
}

// per-column sum & sumsq of bf16 h into st[0..255], st[256..511].
// Grid-stride with fixed per-thread column group (stride % 64 == 0).
__global__ void colstats_k(const unsigned short* __restrict__ h, float* st, int total4) {
    const int gid    = blockIdx.x * 256 + threadIdx.x;
    const int stride = gridDim.x * 256;
    float4 s = {0.f, 0.f, 0.f, 0.f}, q = {0.f, 0.f, 0.f, 0.f};
    for (int i = gid; i < total4; i += stride) {
        ushort4 v = ((const ushort4*)h)[i];
        float x0 = bf2f(v.x), x1 = bf2f(v.y), x2 = bf2f(v.z), x3 = bf2f(v.w);
        s.x += x0; s.y += x1; s.z += x2; s.w += x3;
        q.x += x0 * x0; q.y += x1 * x1; q.z += x2 * x2; q.w += x3 * x3;
    }
    __shared__ float red[2][4][64][4];
    const int wid = threadIdx.x >> 6, lane = threadIdx.x & 63;
    *(float4*)&red[0][wid][lane][0] = s;
    *(float4*)&red[1][wid][lane][0] = q;
    __syncthreads();
    if (wid == 0) {
        float4 s0 = *(float4*)&red[0][0][lane][0];
        float4 q0 = *(float4*)&red[1][0][lane][0];
        #pragma unroll
        for (int w = 1; w < 4; ++w) {
            float4 sw = *(float4*)&red[0][w][lane][0];
            float4 qw = *(float4*)&red[1][w][lane][0];
            s0.x += sw.x; s0.y += sw.y; s0.z += sw.z; s0.w += sw.w;
            q0.x += qw.x; q0.y += qw.y; q0.z += qw.z; q0.w += qw.w;
        }
        atomicAdd(&st[lane * 4 + 0], s0.x);
        atomicAdd(&st[lane * 4 + 1], s0.y);
        atomicAdd(&st[lane * 4 + 2], s0.z);
        atomicAdd(&st[lane * 4 + 3], s0.w);
        atomicAdd(&st[256 + lane * 4 + 0], q0.x);
        atomicAdd(&st[256 + lane * 4 + 1], q0.y);
        atomicAdd(&st[256 + lane * 4 + 2], q0.z);
        atomicAdd(&st[256 + lane * 4 + 3], q0.w);
    }
}

// Fused BN-finalize + BN-apply + ELU. Input bf16, output bf16 or f32 (final).
// Per-thread column group is FIXED (grid stride % 64 == 0), so scale/shift
// are derived from st/g/be once before the loop (no bnfinal kernel needed).
template<bool OUT_F32>
__global__ void bnelu_k(const unsigned short* __restrict__ h,
                        const float* __restrict__ st, const float* __restrict__ g,
                        const float* __restrict__ be, void* __restrict__ outp,
                        int total4, float invN) {
    const int gid    = blockIdx.x * 256 + threadIdx.x;
    const int stride = gridDim.x * 256;        // multiple of 64 by launch config
    const int c      = (gid << 2) & 255;
    float sc[4], sh[4];
    #pragma unroll
    for (int j = 0; j < 4; ++j) {
        float mu  = st[c + j] * invN;
        float var = st[256 + c + j] * invN - mu * mu;
        float s   = g[c + j] * rsqrtf(var + 1e-5f);
        sc[j] = s;
        sh[j] = be[c + j] - mu * s;
    }
    for (int i = gid; i < total4; i += stride) {
        ushort4 v = ((const ushort4*)h)[i];
        float y0 = fmaf(bf2f(v.x), sc[0], sh[0]);
        float y1 = fmaf(bf2f(v.y), sc[1], sh[1]);
        float y2 = fmaf(bf2f(v.z), sc[2], sh[2]);
        float y3 = fmaf(bf2f(v.w), sc[3], sh[3]);
        y0 = y0 > 0.f ? y0 : expm1f(y0);
        y1 = y1 > 0.f ? y1 : expm1f(y1);
        y2 = y2 > 0.f ? y2 : expm1f(y2);
        y3 = y3 > 0.f ? y3 : expm1f(y3);
        if (OUT_F32) {
            float4 o; o.x = y0; o.y = y1; o.z = y2; o.w = y3;
            ((float4*)outp)[i] = o;
        } else {
            ushort4 o;
            o.x = f2bf(y0); o.y = f2bf(y1); o.z = f2bf(y2); o.w = f2bf(y3);
            ((ushort4*)outp)[i] = o;
        }
    }
}

// per-row dot products with att vectors (wave per row)
__global__ void adot_k(const unsigned short* __restrict__ xl, const float* __restrict__ as_,
                       const float* __restrict__ ad_, float* __restrict__ a_src,
                       float* __restrict__ a_dst, int N) {
    int w = (blockIdx.x * blockDim.x + threadIdx.x) >> 6;
    int lane = threadIdx.x & 63;
    if (w >= N) return;
    ushort4 v = *(const ushort4*)(xl + (size_t)w * 256 + lane * 4);
    float4 s4 = *(const float4*)(as_ + lane * 4);
    float4 d4 = *(const float4*)(ad_ + lane * 4);
    float x0 = bf2f(v.x), x1 = bf2f(v.y), x2 = bf2f(v.z), x3 = bf2f(v.w);
    float ps = x0 * s4.x + x1 * s4.y + x2 * s4.z + x3 * s4.w;
    float pd = x0 * d4.x + x1 * d4.y + x2 * d4.z + x3 * d4.w;
    #pragma unroll
    for (int off = 32; off; off >>= 1) {
        ps += __shfl_xor(ps, off);
        pd += __shfl_xor(pd, off);
    }
    if (lane == 0) { a_src[w] = ps; a_dst[w] = pd; }
}

DEV float lrelu(float e) { return e > 0.f ? e : 0.2f * e; }

// one wave per destination node. Pass 1: ONLINE max+sum (single edge sweep).
// Pass 2: weighted gather (x4 unrolled, 4 independent accumulators). bf16 out.
__global__ void gat_k(const unsigned short* __restrict__ xl, const float* __restrict__ a_src,
                      const float* __restrict__ a_dst, const int* __restrict__ csr,
                      const int* __restrict__ indptr, unsigned short* __restrict__ out, int N) {
    int d = (blockIdx.x * blockDim.x + threadIdx.x) >> 6;
    int lane = threadIdx.x & 63;
    if (d >= N) return;
    int beg = indptr[d], end = indptr[d + 1];
    float adst = a_dst[d];

    float m = -1e30f, s = 0.f;
    for (int i = beg + lane; i < end; i += 64) {
        float e  = lrelu(a_src[csr[i]] + adst);
        float nm = fmaxf(m, e);
        s = s * __expf(m - nm) + __expf(e - nm);
        m = nm;
    }
    float mx = m;
    #pragma unroll
    for (int off = 32; off; off >>= 1) mx = fmaxf(mx, __shfl_xor(mx, off));
    s *= __expf(m - mx);
    #pragma unroll
    for (int off = 32; off; off >>= 1) s += __shfl_xor(s, off);
    float inv = 1.f / (s + 1e-16f);

    float4 A0 = {0,0,0,0}, A1 = {0,0,0,0}, A2 = {0,0,0,0}, A3 = {0,0,0,0};
    int i = beg;
    for (; i + 4 <= end; i += 4) {
        int s0 = csr[i], s1 = csr[i+1], s2 = csr[i+2], s3 = csr[i+3];
        float w0 = __expf(lrelu(a_src[s0] + adst) - mx) * inv;
        float w1 = __expf(lrelu(a_src[s1] + adst) - mx) * inv;
        float w2 = __expf(lrelu(a_src[s2] + adst) - mx) * inv;
        float w3 = __expf(lrelu(a_src[s3] + adst) - mx) * inv;
        ushort4 v0 = *(const ushort4*)(xl + (size_t)s0 * 256 + lane * 4);
        ushort4 v1 = *(const ushort4*)(xl + (size_t)s1 * 256 + lane * 4);
        ushort4 v2 = *(const ushort4*)(xl + (size_t)s2 * 256 + lane * 4);
        ushort4 v3 = *(const ushort4*)(xl + (size_t)s3 * 256 + lane * 4);
        A0.x += w0 * bf2f(v0.x); A0.y += w0 * bf2f(v0.y); A0.z += w0 * bf2f(v0.z); A0.w += w0 * bf2f(v0.w);
        A1.x += w1 * bf2f(v1.x); A1.y += w1 * bf2f(v1.y); A1.z += w1 * bf2f(v1.z); A1.w += w1 * bf2f(v1.w);
        A2.x += w2 * bf2f(v2.x); A2.y += w2 * bf2f(v2.y); A2.z += w2 * bf2f(v2.z); A2.w += w2 * bf2f(v2.w);
        A3.x += w3 * bf2f(v3.x); A3.y += w3 * bf2f(v3.y); A3.z += w3 * bf2f(v3.z); A3.w += w3 * bf2f(v3.w);
    }
    for (; i < end; ++i) {
        int sidx = csr[i];
        float w = __expf(lrelu(a_src[sidx] + adst) - mx) * inv;
        ushort4 v = *(const ushort4*)(xl + (size_t)sidx * 256 + lane * 4);
        A0.x += w * bf2f(v.x); A0.y += w * bf2f(v.y);
        A0.z += w * bf2f(v.z); A0.w += w * bf2f(v.w);
    }
    ushort4 o;
    o.x = f2bf(A0.x + A1.x + A2.x + A3.x);
    o.y = f2bf(A0.y + A1.y + A2.y + A3.y);
    o.z = f2bf(A0.z + A1.z + A2.z + A3.z);
    o.w = f2bf(A0.w + A1.w + A2.w + A3.w);
    *(ushort4*)(out + (size_t)d * 256 + lane * 4) = o;
}

// ---- CSR build ----
__global__ void hist_k(const int* __restrict__ edges, int* deg, int E, int N) {
    int total = E + N;
    for (int i = blockIdx.x * blockDim.x + threadIdx.x; i < total;
         i += gridDim.x * blockDim.x) {
        int dd = (i < E) ? edges[E + i] : (i - E);
        atomicAdd(&deg[dd], 1);
    }
}

__global__ void scan1_k(const int* __restrict__ deg, int* iscan, int* bsum, int N) {
    int i = blockIdx.x * 256 + threadIdx.x;
    int lane = threadIdx.x & 63, wid = threadIdx.x >> 6;
    int v = (i < N) ? deg[i] : 0;
    #pragma unroll
    for (int off = 1; off < 64; off <<= 1) {
        int u = __shfl_up(v, off);
        if (lane >= off) v += u;
    }
    __shared__ int wsum[4];
    if (lane == 63) wsum[wid] = v;
    __syncthreads();
    #pragma unroll
    for (int w = 0; w < 3; ++w) if (wid > w) v += wsum[w];
    if (i < N) iscan[i] = v;
    if (threadIdx.x == 255) bsum[blockIdx.x] = v;
}

__global__ void scan2_k(int* bsum, int nb) {   // nb <= 256
    int t = threadIdx.x;
    int lane = t & 63, wid = t >> 6;
    int v = (t < nb) ? bsum[t] : 0;
    int orig = v;
    #pragma unroll
    for (int off = 1; off < 64; off <<= 1) {
        int u = __shfl_up(v, off);
        if (lane >= off) v += u;
    }
    __shared__ int wsum[4];
    if (lane == 63) wsum[wid] = v;
    __syncthreads();
    #pragma unroll
    for (int w = 0; w < 3; ++w) if (wid > w) v += wsum[w];
    if (t < nb) bsum[t] = v - orig;            // exclusive block offsets
}

__global__ void scan3_k(const int* __restrict__ iscan, const int* __restrict__ boff,
                        int* indptr, int N) {
    int i = blockIdx.x * 256 + threadIdx.x;
    if (i < N) indptr[i + 1] = iscan[i] + boff[blockIdx.x];
    if (i == 0) indptr[0] = 0;
}

__global__ void copy_k(const int* __restrict__ a, int* b, int N) {
    for (int i = blockIdx.x * blockDim.x + threadIdx.x; i < N;
         i += gridDim.x * blockDim.x) b[i] = a[i];
}

__global__ void scatter_k(const int* __restrict__ edges, int* pos, int* csr, int E, int N) {
    int total = E + N;
    for (int i = blockIdx.x * blockDim.x + threadIdx.x; i < total;
         i += gridDim.x * blockDim.x) {
        int s  = (i < E) ? edges[i]     : (i - E);
        int dd = (i < E) ? edges[E + i] : (i - E);
        int slot = atomicAdd(&pos[dd], 1);
        csr[slot] = s;
    }
}

// ---------------------------------------------------------------------------
extern "C" void kernel_launch(void* const* d_in, const int* in_sizes, int n_in,
                              void* d_out, int out_size, void* d_ws, size_t ws_size,
                              hipStream_t stream) {
    const float* x     = (const float*)d_in[0];
    const int*   edges = (const int*)d_in[1];
    const float* W1 = (const float*)d_in[2];
    const float* W2 = (const float*)d_in[4];
    const float* W3 = (const float*)d_in[6];
    const float* g1 = (const float*)d_in[8],  *be1 = (const float*)d_in[9];
    const float* g2 = (const float*)d_in[10], *be2 = (const float*)d_in[11];
    const float* g3 = (const float*)d_in[12], *be3 = (const float*)d_in[13];
    const float* Wg1 = (const float*)d_in[14];
    const float* as1 = (const float*)d_in[15], *ad1 = (const float*)d_in[16];
    const float* g4 = (const float*)d_in[18], *be4 = (const float*)d_in[19];
    const float* Wg2 = (const float*)d_in[20];
    const float* as2 = (const float*)d_in[21], *ad2 = (const float*)d_in[22];
    const float* g5 = (const float*)d_in[24], *be5 = (const float*)d_in[25];

    const int N    = out_size / 256;
    const int K1   = in_sizes[0] / N;
    const int E    = in_sizes[1] / 2;
    const int Etot = E + N;
    const int ks1  = (K1 + 63) / 64;
    const int ldb1 = ks1 * 64;                // padded K (2624)

    // workspace carve (256B aligned)
    char* p = (char*)d_ws;
    auto alloc = [&](size_t bytes) {
        char* r = p;
        p += (bytes + 255) & ~(size_t)255;
        return r;
    };
    unsigned short* W1T  = (unsigned short*)alloc((size_t)256 * ldb1 * 2);
    unsigned short* W2T  = (unsigned short*)alloc(256 * 256 * 2);
    unsigned short* W3T  = (unsigned short*)alloc(256 * 256 * 2);
    unsigned short* Wg1T = (unsigned short*)alloc(256 * 256 * 2);
    unsigned short* Wg2T = (unsigned short*)alloc(256 * 256 * 2);
    unsigned short* xb   = (unsigned short*)alloc((size_t)N * ldb1 * 2);  // bf16 x, padded
    unsigned short* ha   = (unsigned short*)alloc((size_t)N * 256 * 2);
    unsigned short* hb   = (unsigned short*)alloc((size_t)N * 256 * 2);
    unsigned short* xl   = (unsigned short*)alloc((size_t)N * 256 * 2);
    float* a_src  = (float*)alloc((size_t)N * 4);
    float* a_dst  = (float*)alloc((size_t)N * 4);
    int*   deg    = (int*)alloc((size_t)N * 4);
    int*   iscan  = (int*)alloc((size_t)N * 4);
    int*   bsum   = (int*)alloc(1024);
    int*   indptr = (int*)alloc((size_t)(N + 1) * 4);
    int*   pos    = (int*)alloc((size_t)N * 4);
    int*   csr    = (int*)alloc((size_t)Etot * 4);
    float* st     = (float*)alloc(512 * 4);
    (void)alloc(1 << 19); // 512KB tail guard (benign OOB reads of last tile rows)
    float* out = (float*)d_out;

    const int nb = (N + 255) / 256;
    const int eg = (Etot + 255) / 256;
    const int gb = (N + 127) / 128;           // 128-row GEMM blocks
    const int t4 = N * 64;                    // (N*256)/4
    const float invN = 1.f / (float)N;

    // ---- graph CSR (shared by both GAT layers) ----
    hipMemsetAsync(deg, 0, (size_t)N * 4, stream);
    hist_k<<<eg, 256, 0, stream>>>(edges, deg, E, N);
    scan1_k<<<nb, 256, 0, stream>>>(deg, iscan, bsum, N);
    scan2_k<<<1, 256, 0, stream>>>(bsum, nb);
    scan3_k<<<nb, 256, 0, stream>>>(iscan, bsum, indptr, N);
    copy_k<<<nb, 256, 0, stream>>>(indptr, pos, N);
    scatter_k<<<eg, 256, 0, stream>>>(edges, pos, csr, E, N);

    // ---- weight prep (transpose + bf16) + x conversion ----
    wtrans_k<<<(256 * ldb1 + 255) / 256, 256, 0, stream>>>(W1, W1T, K1, ldb1);
    wtrans_k<<<256, 256, 0, stream>>>(W2, W2T, 256, 256);
    wtrans_k<<<256, 256, 0, stream>>>(W3, W3T, 256, 256);
    wtrans_k<<<256, 256, 0, stream>>>(Wg1, Wg1T, 256, 256);
    wtrans_k<<<256, 256, 0, stream>>>(Wg2, Wg2T, 256, 256);
    cvt_pad_k<<<2048, 256, 0, stream>>>(x, xb, N, K1, ldb1);

    // ---- layer 1: x @ W1 -> BN -> ELU (bias cancels in BN; stats fused) ----
    hipMemsetAsync(st, 0, 2048, stream);
    gemm_k<true><<<gb, 512, 0, stream>>>(xb, W1T, ha, st, N, ldb1, ldb1, ks1);
    bnelu_k<false><<<2048, 256, 0, stream>>>(ha, st, g1, be1, ha, t4, invN);

    // ---- layer 2 ----
    hipMemsetAsync(st, 0, 2048, stream);
    gemm_k<true><<<gb, 512, 0, stream>>>(ha, W2T, hb, st, N, 256, 256, 4);
    bnelu_k<false><<<2048, 256, 0, stream>>>(hb, st, g2, be2, hb, t4, invN);

    // ---- layer 3 ----
    hipMemsetAsync(st, 0, 2048, stream);
    gemm_k<true><<<gb, 512, 0, stream>>>(hb, W3T, ha, st, N, 256, 256, 4);
    bnelu_k<false><<<2048, 256, 0, stream>>>(ha, st, g3, be3, ha, t4, invN);

    // ---- GAT layer 1 ----
    gemm_k<false><<<gb, 512, 0, stream>>>(ha, Wg1T, xl, st, N, 256, 256, 4);
    adot_k<<<(N + 3) / 4, 256, 0, stream>>>(xl, as1, ad1, a_src, a_dst, N);
    gat_k<<<(N + 3) / 4, 256, 0, stream>>>(xl, a_src, a_dst, csr, indptr, hb, N);
    hipMemsetAsync(st, 0, 2048, stream);
    colstats_k<<<1024, 256, 0, stream>>>(hb, st, t4);
    bnelu_k<false><<<2048, 256, 0, stream>>>(hb, st, g4, be4, hb, t4, invN);

    // ---- GAT layer 2 ----
    gemm_k<false><<<gb, 512, 0, stream>>>(hb, Wg2T, xl, st, N, 256, 256, 4);
    adot_k<<<(N + 3) / 4, 256, 0, stream>>>(xl, as2, ad2, a_src, a_dst, N);
    gat_k<<<(N + 3) / 4, 256, 0, stream>>>(xl, a_src, a_dst, csr, indptr, ha, N);
    hipMemsetAsync(st, 0, 2048, stream);
    colstats_k<<<1024, 256, 0, stream>>>(ha, st, t4);
    bnelu_k<true><<<2048, 256, 0, stream>>>(ha, st, g5, be5, out, t4, invN);  // final f32
}

// Round 7
// 940.910 us; speedup vs baseline: 1.5297x; 1.0271x over previous
//
#include <hip/hip_runtime.h>

#define DEV __device__ __forceinline__

typedef __attribute__((ext_vector_type(4))) float f32x4;
typedef __attribute__((ext_vector_type(8))) short short8;

DEV float bf2f(unsigned short u) {
    union { unsigned int i; float f; } c;
    c.i = ((unsigned int)u) << 16;
    return c.f;
}
DEV unsigned short f2bf(float f) {
    union { float f; unsigned int i; } c;
    c.f = f;
    unsigned int u = c.i;
    u += 0x7FFFu + ((u >> 16) & 1u);   // RTNE (finite values only here)
    return (unsigned short)(u >> 16);
}

// ---------------------------------------------------------------------------
// prep_k: one kernel for ALL weight prep + x conversion.
//   blocks [0, XB_B):    x f32[M][K1] -> xb bf16[M][ldb1] (zero-padded)
//   blocks [XB_B, grid): 5 weight transposes W[K,256] -> WT[256][ldb] bf16
//     over a concatenated index space [W1T | W2T | W3T | Wg1T | Wg2T]
//     (dst regions are CONTIGUOUS in ws starting at W1T).
// ---------------------------------------------------------------------------
#define XB_B 2048
__global__ void prep_k(const float* __restrict__ x,
                       const float* __restrict__ W1, const float* __restrict__ W2,
                       const float* __restrict__ W3, const float* __restrict__ Wg1,
                       const float* __restrict__ Wg2,
                       unsigned short* __restrict__ xb,
                       unsigned short* __restrict__ WTbase,
                       int M, int K1, int ldb1) {
    if (blockIdx.x < XB_B) {
        const int gpr = ldb1 >> 3;
        const long long total = (long long)M * gpr;
        for (long long g = blockIdx.x * (long long)blockDim.x + threadIdx.x; g < total;
             g += (long long)XB_B * blockDim.x) {
            const int row = (int)(g / gpr);
            const int c8  = (int)(g - (long long)row * gpr);
            const int k0  = c8 * 8;
            const float* src = x + (size_t)row * K1 + k0;
            unsigned int w[4];
            if (k0 + 8 <= K1) {
                f32x4 v0 = *(const f32x4*)(src);
                f32x4 v1 = *(const f32x4*)(src + 4);
                w[0] = (unsigned int)f2bf(v0[0]) | ((unsigned int)f2bf(v0[1]) << 16);
                w[1] = (unsigned int)f2bf(v0[2]) | ((unsigned int)f2bf(v0[3]) << 16);
                w[2] = (unsigned int)f2bf(v1[0]) | ((unsigned int)f2bf(v1[1]) << 16);
                w[3] = (unsigned int)f2bf(v1[2]) | ((unsigned int)f2bf(v1[3]) << 16);
            } else {
                unsigned short o[8];
                #pragma unroll
                for (int j = 0; j < 8; ++j) o[j] = (k0 + j < K1) ? f2bf(src[j]) : (unsigned short)0;
                w[0] = o[0] | ((unsigned int)o[1] << 16);
                w[1] = o[2] | ((unsigned int)o[3] << 16);
                w[2] = o[4] | ((unsigned int)o[5] << 16);
                w[3] = o[6] | ((unsigned int)o[7] << 16);
            }
            *(uint4*)(xb + (size_t)row * ldb1 + k0) = *(uint4*)w;
        }
    } else {
        const int w1n   = 256 * ldb1;                  // W1T elems
        const int total = w1n + 4 * 65536;
        const int wblk  = gridDim.x - XB_B;
        for (int idx = (blockIdx.x - XB_B) * blockDim.x + threadIdx.x; idx < total;
             idx += wblk * blockDim.x) {
            const float* W; int K, ldb, i;
            if (idx < w1n) { W = W1; K = K1; ldb = ldb1; i = idx; }
            else {
                int r = (idx - w1n) >> 16;
                i = (idx - w1n) & 65535;
                W = (r == 0) ? W2 : (r == 1) ? W3 : (r == 2) ? Wg1 : Wg2;
                K = 256; ldb = 256;
            }
            int n = i / ldb, k = i - n * ldb;
            WTbase[idx] = f2bf(k < K ? W[(size_t)k * 256 + n] : 0.f);
        }
    }
}

// ---------------------------------------------------------------------------
// GEMM: C[M,256] = A[M,K] @ B[K,256]; A bf16 [M][lda], B bf16 Bt[256][ldb].
// BM=128, BN=256, BK=64, 512 threads = 8 waves (2x4), 64x64 C tile per wave.
// DEPTH-3 counted-vmcnt pipeline (3 LDS bufs, 144KB), 6 vmem/wave/tile.
// STATS: fused per-column BN sum/sumsq (f32-exact). ADOT: fused per-row dot
// products with attention vectors (replaces adot_k), atomicAdd into a_src/dst.
// LDS [row][chunk] with chunk XOR-swizzle (c ^= row&7), chunk = 8 bf16.
// ---------------------------------------------------------------------------
template<bool STATS, bool ADOT>
__launch_bounds__(512)
__global__ void gemm_k(const unsigned short* __restrict__ A,
                       const unsigned short* __restrict__ Bt,
                       unsigned short* __restrict__ C,
                       float* __restrict__ st,
                       const float* __restrict__ avs, const float* __restrict__ avd,
                       float* __restrict__ a_src, float* __restrict__ a_dst,
                       int M, int lda, int ldb, int ksteps)
{
    __shared__ __align__(16) unsigned short As[3][128 * 64];
    __shared__ __align__(16) unsigned short Bs[3][256 * 64];
    const int t    = threadIdx.x;
    const int wid  = t >> 6;       // 0..7
    const int lane = t & 63;
    const int wr   = wid >> 2;     // 0..1  (64-row band)
    const int wc   = wid & 3;      // 0..3  (64-col band)
    const int m0   = blockIdx.x * 128;

    f32x4 acc[4][4] = {};

    auto stage = [&](int buf, int ks) {        // 6 global_load_lds per wave
        const int k0 = ks * 64;
        #pragma unroll
        for (int is = 0; is < 2; ++is) {       // A: 128x64 tile
            const int rbase = wid * 16 + is * 8;
            const int rr  = rbase + (lane >> 3);
            const int csw = (lane & 7) ^ (rr & 7);
            __builtin_amdgcn_global_load_lds(
                (const __attribute__((address_space(1))) void*)(A + (size_t)(m0 + rr) * lda + k0 + csw * 8),
                (__attribute__((address_space(3))) void*)(&As[buf][rbase * 64]),
                16, 0, 0);
        }
        #pragma unroll
        for (int is = 0; is < 4; ++is) {       // B: 256x64 tile
            const int rbase = wid * 32 + is * 8;
            const int rr  = rbase + (lane >> 3);
            const int csw = (lane & 7) ^ (rr & 7);
            __builtin_amdgcn_global_load_lds(
                (const __attribute__((address_space(1))) void*)(Bt + (size_t)rr * ldb + k0 + csw * 8),
                (__attribute__((address_space(3))) void*)(&Bs[buf][rbase * 64]),
                16, 0, 0);
        }
    };
    auto compute = [&](int buf) {
        #pragma unroll
        for (int kk = 0; kk < 2; ++kk) {
            short8 af[4], bfr[4];
            #pragma unroll
            for (int mi = 0; mi < 4; ++mi) {
                const int r   = wr * 64 + mi * 16 + (lane & 15);
                const int csw = (kk * 4 + (lane >> 4)) ^ (r & 7);
                af[mi] = *(const short8*)(&As[buf][r * 64 + csw * 8]);
            }
            #pragma unroll
            for (int ni = 0; ni < 4; ++ni) {
                const int r   = wc * 64 + ni * 16 + (lane & 15);
                const int csw = (kk * 4 + (lane >> 4)) ^ (r & 7);
                bfr[ni] = *(const short8*)(&Bs[buf][r * 64 + csw * 8]);
            }
            __builtin_amdgcn_s_setprio(1);
            #pragma unroll
            for (int mi = 0; mi < 4; ++mi)
                #pragma unroll
                for (int ni = 0; ni < 4; ++ni)
                    acc[mi][ni] = __builtin_amdgcn_mfma_f32_16x16x32_bf16(
                        af[mi], bfr[ni], acc[mi][ni], 0, 0, 0);
            __builtin_amdgcn_s_setprio(0);
        }
    };

    // ---- prologue: tiles 0,1,2 in flight (ksteps >= 3) ----
    stage(0, 0);
    __builtin_amdgcn_sched_barrier(0);
    stage(1, 1);
    __builtin_amdgcn_sched_barrier(0);
    stage(2, 2);
    asm volatile("s_waitcnt vmcnt(12)" ::: "memory");   // tile 0 landed
    __builtin_amdgcn_sched_barrier(0);
    __builtin_amdgcn_s_barrier();
    __builtin_amdgcn_sched_barrier(0);

    // ---- main loop ----
    int cur = 0;
    for (int k = 0; k < ksteps; ++k) {
        compute(cur);                            // tile k from buf[cur]
        if (k + 1 >= ksteps) break;
        __builtin_amdgcn_sched_barrier(0);
        __builtin_amdgcn_s_barrier();            // buf[cur] free for overwrite
        __builtin_amdgcn_sched_barrier(0);
        if (k + 3 < ksteps) {
            stage(cur, k + 3);
            asm volatile("s_waitcnt vmcnt(12)" ::: "memory");  // tile k+1 landed
        } else if (k + 2 < ksteps) {
            asm volatile("s_waitcnt vmcnt(6)" ::: "memory");   // tile k+1 landed
        } else {
            asm volatile("s_waitcnt vmcnt(0)" ::: "memory");
        }
        __builtin_amdgcn_sched_barrier(0);
        __builtin_amdgcn_s_barrier();            // next buf ready
        __builtin_amdgcn_sched_barrier(0);
        cur = (cur == 2) ? 0 : cur + 1;
    }

    // ---- epilogue: bf16 C; col = lane&15 of band, row = (lane>>4)*4 + rg ----
    #pragma unroll
    for (int mi = 0; mi < 4; ++mi) {
        #pragma unroll
        for (int ni = 0; ni < 4; ++ni) {
            const int col = wc * 64 + ni * 16 + (lane & 15);
            #pragma unroll
            for (int rg = 0; rg < 4; ++rg) {
                const int m = m0 + wr * 64 + mi * 16 + (lane >> 4) * 4 + rg;
                if (m < M)
                    C[(size_t)m * 256 + col] = f2bf(acc[mi][ni][rg]);
            }
        }
    }
    if constexpr (STATS) {    // fused BN column stats (sum, sumsq), f32-exact
        #pragma unroll
        for (int ni = 0; ni < 4; ++ni) {
            float s = 0.f, q = 0.f;
            #pragma unroll
            for (int mi = 0; mi < 4; ++mi)
                #pragma unroll
                for (int rg = 0; rg < 4; ++rg) {
                    const int m = m0 + wr * 64 + mi * 16 + (lane >> 4) * 4 + rg;
                    const float v = (m < M) ? acc[mi][ni][rg] : 0.f;
                    s += v; q += v * v;
                }
            s += __shfl_xor(s, 16); q += __shfl_xor(q, 16);
            s += __shfl_xor(s, 32); q += __shfl_xor(q, 32);
            if (lane < 16) {
                const int col = wc * 64 + ni * 16 + lane;
                atomicAdd(&st[col], s);
                atomicAdd(&st[256 + col], q);
            }
        }
    }
    if constexpr (ADOT) {     // fused per-row attention dots (from f32 acc)
        #pragma unroll
        for (int mi = 0; mi < 4; ++mi) {
            float ps[4] = {0.f, 0.f, 0.f, 0.f};
            float pd[4] = {0.f, 0.f, 0.f, 0.f};
            #pragma unroll
            for (int ni = 0; ni < 4; ++ni) {
                const int col = wc * 64 + ni * 16 + (lane & 15);
                const float a_s = avs[col], a_d = avd[col];
                #pragma unroll
                for (int rg = 0; rg < 4; ++rg) {
                    ps[rg] += acc[mi][ni][rg] * a_s;
                    pd[rg] += acc[mi][ni][rg] * a_d;
                }
            }
            #pragma unroll
            for (int rg = 0; rg < 4; ++rg) {
                #pragma unroll
                for (int off = 1; off < 16; off <<= 1) {
                    ps[rg] += __shfl_xor(ps[rg], off);
                    pd[rg] += __shfl_xor(pd[rg], off);
                }
                const int m = m0 + wr * 64 + mi * 16 + (lane >> 4) * 4 + rg;
                if ((lane & 15) == 0 && m < M) {
                    atomicAdd(&a_src[m], ps[rg]);
                    atomicAdd(&a_dst[m], pd[rg]);
                }
            }
        }
    }
}

// per-column sum & sumsq of bf16 h into st[0..255], st[256..511].
__global__ void colstats_k(const unsigned short* __restrict__ h, float* st, int total4) {
    const int gid    = blockIdx.x * 256 + threadIdx.x;
    const int stride = gridDim.x * 256;
    float4 s = {0.f, 0.f, 0.f, 0.f}, q = {0.f, 0.f, 0.f, 0.f};
    for (int i = gid; i < total4; i += stride) {
        ushort4 v = ((const ushort4*)h)[i];
        float x0 = bf2f(v.x), x1 = bf2f(v.y), x2 = bf2f(v.z), x3 = bf2f(v.w);
        s.x += x0; s.y += x1; s.z += x2; s.w += x3;
        q.x += x0 * x0; q.y += x1 * x1; q.z += x2 * x2; q.w += x3 * x3;
    }
    __shared__ float red[2][4][64][4];
    const int wid = threadIdx.x >> 6, lane = threadIdx.x & 63;
    *(float4*)&red[0][wid][lane][0] = s;
    *(float4*)&red[1][wid][lane][0] = q;
    __syncthreads();
    if (wid == 0) {
        float4 s0 = *(float4*)&red[0][0][lane][0];
        float4 q0 = *(float4*)&red[1][0][lane][0];
        #pragma unroll
        for (int w = 1; w < 4; ++w) {
            float4 sw = *(float4*)&red[0][w][lane][0];
            float4 qw = *(float4*)&red[1][w][lane][0];
            s0.x += sw.x; s0.y += sw.y; s0.z += sw.z; s0.w += sw.w;
            q0.x += qw.x; q0.y += qw.y; q0.z += qw.z; q0.w += qw.w;
        }
        atomicAdd(&st[lane * 4 + 0], s0.x);
        atomicAdd(&st[lane * 4 + 1], s0.y);
        atomicAdd(&st[lane * 4 + 2], s0.z);
        atomicAdd(&st[lane * 4 + 3], s0.w);
        atomicAdd(&st[256 + lane * 4 + 0], q0.x);
        atomicAdd(&st[256 + lane * 4 + 1], q0.y);
        atomicAdd(&st[256 + lane * 4 + 2], q0.z);
        atomicAdd(&st[256 + lane * 4 + 3], q0.w);
    }
}

// Fused BN-finalize + BN-apply + ELU. Input bf16, output bf16 or f32 (final).
template<bool OUT_F32>
__global__ void bnelu_k(const unsigned short* __restrict__ h,
                        const float* __restrict__ st, const float* __restrict__ g,
                        const float* __restrict__ be, void* __restrict__ outp,
                        int total4, float invN) {
    const int gid    = blockIdx.x * 256 + threadIdx.x;
    const int stride = gridDim.x * 256;        // multiple of 64 by launch config
    const int c      = (gid << 2) & 255;
    float sc[4], sh[4];
    #pragma unroll
    for (int j = 0; j < 4; ++j) {
        float mu  = st[c + j] * invN;
        float var = st[256 + c + j] * invN - mu * mu;
        float s   = g[c + j] * rsqrtf(var + 1e-5f);
        sc[j] = s;
        sh[j] = be[c + j] - mu * s;
    }
    for (int i = gid; i < total4; i += stride) {
        ushort4 v = ((const ushort4*)h)[i];
        float y0 = fmaf(bf2f(v.x), sc[0], sh[0]);
        float y1 = fmaf(bf2f(v.y), sc[1], sh[1]);
        float y2 = fmaf(bf2f(v.z), sc[2], sh[2]);
        float y3 = fmaf(bf2f(v.w), sc[3], sh[3]);
        y0 = y0 > 0.f ? y0 : expm1f(y0);
        y1 = y1 > 0.f ? y1 : expm1f(y1);
        y2 = y2 > 0.f ? y2 : expm1f(y2);
        y3 = y3 > 0.f ? y3 : expm1f(y3);
        if (OUT_F32) {
            float4 o; o.x = y0; o.y = y1; o.z = y2; o.w = y3;
            ((float4*)outp)[i] = o;
        } else {
            ushort4 o;
            o.x = f2bf(y0); o.y = f2bf(y1); o.z = f2bf(y2); o.w = f2bf(y3);
            ((ushort4*)outp)[i] = o;
        }
    }
}

DEV float lrelu(float e) { return e > 0.f ? e : 0.2f * e; }

// one wave per destination node. Pass 1: online max+sum. Pass 2: weighted
// gather (x4 unrolled, independent accumulators). bf16 out.
__global__ void gat_k(const unsigned short* __restrict__ xl, const float* __restrict__ a_src,
                      const float* __restrict__ a_dst, const int* __restrict__ csr,
                      const int* __restrict__ indptr, unsigned short* __restrict__ out, int N) {
    int d = (blockIdx.x * blockDim.x + threadIdx.x) >> 6;
    int lane = threadIdx.x & 63;
    if (d >= N) return;
    int beg = indptr[d], end = indptr[d + 1];
    float adst = a_dst[d];

    float m = -1e30f, s = 0.f;
    for (int i = beg + lane; i < end; i += 64) {
        float e  = lrelu(a_src[csr[i]] + adst);
        float nm = fmaxf(m, e);
        s = s * __expf(m - nm) + __expf(e - nm);
        m = nm;
    }
    float mx = m;
    #pragma unroll
    for (int off = 32; off; off >>= 1) mx = fmaxf(mx, __shfl_xor(mx, off));
    s *= __expf(m - mx);
    #pragma unroll
    for (int off = 32; off; off >>= 1) s += __shfl_xor(s, off);
    float inv = 1.f / (s + 1e-16f);

    float4 A0 = {0,0,0,0}, A1 = {0,0,0,0}, A2 = {0,0,0,0}, A3 = {0,0,0,0};
    int i = beg;
    for (; i + 4 <= end; i += 4) {
        int s0 = csr[i], s1 = csr[i+1], s2 = csr[i+2], s3 = csr[i+3];
        float w0 = __expf(lrelu(a_src[s0] + adst) - mx) * inv;
        float w1 = __expf(lrelu(a_src[s1] + adst) - mx) * inv;
        float w2 = __expf(lrelu(a_src[s2] + adst) - mx) * inv;
        float w3 = __expf(lrelu(a_src[s3] + adst) - mx) * inv;
        ushort4 v0 = *(const ushort4*)(xl + (size_t)s0 * 256 + lane * 4);
        ushort4 v1 = *(const ushort4*)(xl + (size_t)s1 * 256 + lane * 4);
        ushort4 v2 = *(const ushort4*)(xl + (size_t)s2 * 256 + lane * 4);
        ushort4 v3 = *(const ushort4*)(xl + (size_t)s3 * 256 + lane * 4);
        A0.x += w0 * bf2f(v0.x); A0.y += w0 * bf2f(v0.y); A0.z += w0 * bf2f(v0.z); A0.w += w0 * bf2f(v0.w);
        A1.x += w1 * bf2f(v1.x); A1.y += w1 * bf2f(v1.y); A1.z += w1 * bf2f(v1.z); A1.w += w1 * bf2f(v1.w);
        A2.x += w2 * bf2f(v2.x); A2.y += w2 * bf2f(v2.y); A2.z += w2 * bf2f(v2.z); A2.w += w2 * bf2f(v2.w);
        A3.x += w3 * bf2f(v3.x); A3.y += w3 * bf2f(v3.y); A3.z += w3 * bf2f(v3.z); A3.w += w3 * bf2f(v3.w);
    }
    for (; i < end; ++i) {
        int sidx = csr[i];
        float w = __expf(lrelu(a_src[sidx] + adst) - mx) * inv;
        ushort4 v = *(const ushort4*)(xl + (size_t)sidx * 256 + lane * 4);
        A0.x += w * bf2f(v.x); A0.y += w * bf2f(v.y);
        A0.z += w * bf2f(v.z); A0.w += w * bf2f(v.w);
    }
    ushort4 o;
    o.x = f2bf(A0.x + A1.x + A2.x + A3.x);
    o.y = f2bf(A0.y + A1.y + A2.y + A3.y);
    o.z = f2bf(A0.z + A1.z + A2.z + A3.z);
    o.w = f2bf(A0.w + A1.w + A2.w + A3.w);
    *(ushort4*)(out + (size_t)d * 256 + lane * 4) = o;
}

// ---- CSR build ----
__global__ void hist_k(const int* __restrict__ edges, int* deg, int E, int N) {
    int total = E + N;
    for (int i = blockIdx.x * blockDim.x + threadIdx.x; i < total;
         i += gridDim.x * blockDim.x) {
        int dd = (i < E) ? edges[E + i] : (i - E);
        atomicAdd(&deg[dd], 1);
    }
}

__global__ void scan1_k(const int* __restrict__ deg, int* iscan, int* bsum, int N) {
    int i = blockIdx.x * 256 + threadIdx.x;
    int lane = threadIdx.x & 63, wid = threadIdx.x >> 6;
    int v = (i < N) ? deg[i] : 0;
    #pragma unroll
    for (int off = 1; off < 64; off <<= 1) {
        int u = __shfl_up(v, off);
        if (lane >= off) v += u;
    }
    __shared__ int wsum[4];
    if (lane == 63) wsum[wid] = v;
    __syncthreads();
    #pragma unroll
    for (int w = 0; w < 3; ++w) if (wid > w) v += wsum[w];
    if (i < N) iscan[i] = v;
    if (threadIdx.x == 255) bsum[blockIdx.x] = v;
}

__global__ void scan2_k(int* bsum, int nb) {   // nb <= 256
    int t = threadIdx.x;
    int lane = t & 63, wid = t >> 6;
    int v = (t < nb) ? bsum[t] : 0;
    int orig = v;
    #pragma unroll
    for (int off = 1; off < 64; off <<= 1) {
        int u = __shfl_up(v, off);
        if (lane >= off) v += u;
    }
    __shared__ int wsum[4];
    if (lane == 63) wsum[wid] = v;
    __syncthreads();
    #pragma unroll
    for (int w = 0; w < 3; ++w) if (wid > w) v += wsum[w];
    if (t < nb) bsum[t] = v - orig;            // exclusive block offsets
}

// indptr[i+1] = inclusive_scan[i]; pos[i] = indptr[i+1] - deg[i] ( = indptr[i] )
__global__ void scan3copy_k(const int* __restrict__ iscan, const int* __restrict__ boff,
                            const int* __restrict__ deg, int* indptr, int* pos, int N) {
    int i = blockIdx.x * 256 + threadIdx.x;
    if (i < N) {
        int v = iscan[i] + boff[blockIdx.x];
        indptr[i + 1] = v;
        pos[i] = v - deg[i];
    }
    if (i == 0) indptr[0] = 0;
}

__global__ void scatter_k(const int* __restrict__ edges, int* pos, int* csr, int E, int N) {
    int total = E + N;
    for (int i = blockIdx.x * blockDim.x + threadIdx.x; i < total;
         i += gridDim.x * blockDim.x) {
        int s  = (i < E) ? edges[i]     : (i - E);
        int dd = (i < E) ? edges[E + i] : (i - E);
        int slot = atomicAdd(&pos[dd], 1);
        csr[slot] = s;
    }
}

// ---------------------------------------------------------------------------
extern "C" void kernel_launch(void* const* d_in, const int* in_sizes, int n_in,
                              void* d_out, int out_size, void* d_ws, size_t ws_size,
                              hipStream_t stream) {
    const float* x     = (const float*)d_in[0];
    const int*   edges = (const int*)d_in[1];
    const float* W1 = (const float*)d_in[2];
    const float* W2 = (const float*)d_in[4];
    const float* W3 = (const float*)d_in[6];
    const float* g1 = (const float*)d_in[8],  *be1 = (const float*)d_in[9];
    const float* g2 = (const float*)d_in[10], *be2 = (const float*)d_in[11];
    const float* g3 = (const float*)d_in[12], *be3 = (const float*)d_in[13];
    const float* Wg1 = (const float*)d_in[14];
    const float* as1 = (const float*)d_in[15], *ad1 = (const float*)d_in[16];
    const float* g4 = (const float*)d_in[18], *be4 = (const float*)d_in[19];
    const float* Wg2 = (const float*)d_in[20];
    const float* as2 = (const float*)d_in[21], *ad2 = (const float*)d_in[22];
    const float* g5 = (const float*)d_in[24], *be5 = (const float*)d_in[25];

    const int N    = out_size / 256;
    const int K1   = in_sizes[0] / N;
    const int E    = in_sizes[1] / 2;
    const int Etot = E + N;
    const int ks1  = (K1 + 63) / 64;
    const int ldb1 = ks1 * 64;                // padded K (2624)

    // workspace carve (256B aligned)
    char* p = (char*)d_ws;
    auto alloc = [&](size_t bytes) {
        char* r = p;
        p += (bytes + 255) & ~(size_t)255;
        return r;
    };
    // WT regions CONTIGUOUS (prep_k writes them through one base pointer)
    unsigned short* W1T  = (unsigned short*)alloc((size_t)256 * ldb1 * 2);
    unsigned short* W2T  = (unsigned short*)alloc(256 * 256 * 2);
    unsigned short* W3T  = (unsigned short*)alloc(256 * 256 * 2);
    unsigned short* Wg1T = (unsigned short*)alloc(256 * 256 * 2);
    unsigned short* Wg2T = (unsigned short*)alloc(256 * 256 * 2);
    unsigned short* xb   = (unsigned short*)alloc((size_t)N * ldb1 * 2);  // bf16 x, padded
    unsigned short* ha   = (unsigned short*)alloc((size_t)N * 256 * 2);
    unsigned short* hb   = (unsigned short*)alloc((size_t)N * 256 * 2);
    unsigned short* xl   = (unsigned short*)alloc((size_t)N * 256 * 2);
    // ---- zero region (one memset): [deg | st x5 | asrc1 adst1 asrc2 adst2] --
    char* zero_base = p;
    int*   deg    = (int*)alloc((size_t)N * 4);
    float* st     = (float*)alloc(5 * 512 * 4);
    float* asrc1  = (float*)alloc((size_t)N * 4);
    float* adst1  = (float*)alloc((size_t)N * 4);
    float* asrc2  = (float*)alloc((size_t)N * 4);
    float* adst2  = (float*)alloc((size_t)N * 4);
    size_t zero_bytes = (size_t)(p - zero_base);
    // ---- non-zeroed scratch ----
    int*   iscan  = (int*)alloc((size_t)N * 4);
    int*   bsum   = (int*)alloc(1024);
    int*   indptr = (int*)alloc((size_t)(N + 1) * 4);
    int*   pos    = (int*)alloc((size_t)N * 4);
    int*   csr    = (int*)alloc((size_t)Etot * 4);
    (void)alloc(1 << 19); // 512KB tail guard (benign OOB reads of last tile rows)
    float* out = (float*)d_out;

    const int nb = (N + 255) / 256;
    const int eg = (Etot + 255) / 256;
    const int gb = (N + 127) / 128;           // 128-row GEMM blocks
    const int t4 = N * 64;                    // (N*256)/4
    const float invN = 1.f / (float)N;

    // ---- one upfront zero of all accumulation buffers ----
    hipMemsetAsync(zero_base, 0, zero_bytes, stream);

    // ---- graph CSR (shared by both GAT layers) ----
    hist_k<<<eg, 256, 0, stream>>>(edges, deg, E, N);
    scan1_k<<<nb, 256, 0, stream>>>(deg, iscan, bsum, N);
    scan2_k<<<1, 256, 0, stream>>>(bsum, nb);
    scan3copy_k<<<nb, 256, 0, stream>>>(iscan, bsum, deg, indptr, pos, N);
    scatter_k<<<eg, 256, 0, stream>>>(edges, pos, csr, E, N);

    // ---- all weight transposes + x conversion in ONE kernel ----
    prep_k<<<XB_B + 1600, 256, 0, stream>>>(x, W1, W2, W3, Wg1, Wg2,
                                            xb, W1T, N, K1, ldb1);

    // ---- layer 1..3: GEMM(+stats) -> BN+ELU ----
    gemm_k<true, false><<<gb, 512, 0, stream>>>(xb, W1T, ha, st, nullptr, nullptr,
                                                nullptr, nullptr, N, ldb1, ldb1, ks1);
    bnelu_k<false><<<2048, 256, 0, stream>>>(ha, st, g1, be1, ha, t4, invN);

    gemm_k<true, false><<<gb, 512, 0, stream>>>(ha, W2T, hb, st + 512, nullptr, nullptr,
                                                nullptr, nullptr, N, 256, 256, 4);
    bnelu_k<false><<<2048, 256, 0, stream>>>(hb, st + 512, g2, be2, hb, t4, invN);

    gemm_k<true, false><<<gb, 512, 0, stream>>>(hb, W3T, ha, st + 1024, nullptr, nullptr,
                                                nullptr, nullptr, N, 256, 256, 4);
    bnelu_k<false><<<2048, 256, 0, stream>>>(ha, st + 1024, g3, be3, ha, t4, invN);

    // ---- GAT layer 1 (adot fused into GEMM epilogue) ----
    gemm_k<false, true><<<gb, 512, 0, stream>>>(ha, Wg1T, xl, nullptr, as1, ad1,
                                                asrc1, adst1, N, 256, 256, 4);
    gat_k<<<(N + 3) / 4, 256, 0, stream>>>(xl, asrc1, adst1, csr, indptr, hb, N);
    colstats_k<<<1024, 256, 0, stream>>>(hb, st + 1536, t4);
    bnelu_k<false><<<2048, 256, 0, stream>>>(hb, st + 1536, g4, be4, hb, t4, invN);

    // ---- GAT layer 2 ----
    gemm_k<false, true><<<gb, 512, 0, stream>>>(hb, Wg2T, xl, nullptr, as2, ad2,
                                                asrc2, adst2, N, 256, 256, 4);
    gat_k<<<(N + 3) / 4, 256, 0, stream>>>(xl, asrc2, adst2, csr, indptr, ha, N);
    colstats_k<<<1024, 256, 0, stream>>>(ha, st + 2048, t4);
    bnelu_k<true><<<2048, 256, 0, stream>>>(ha, st + 2048, g5, be5, out, t4, invN);  // final f32
}